// Round 3
// baseline (370.340 us; speedup 1.0000x reference)
//
#include <hip/hip_runtime.h>
#include <hip/hip_bf16.h>

#define N_NODES 50000
#define N_EDGES 400000
#define IN_DIM 128
#define HID 64
#define HEADS 4
#define L1_OUT (HEADS * HID)   // 256
#define OUT_DIM 64
#define NEG_SLOPE 0.2f

#define NB1 32   // nodes per block, gemm1
#define NB2 32   // nodes per block, gemm2
#define XS_STRIDE 36   // pad keeps 16B alignment for float4 LDS reads
#define RS_STRIDE 36
#define SCAN_B 256
#define DCHUNK 128

__device__ __forceinline__ float leaky(float x) { return x > 0.f ? x : NEG_SLOPE * x; }

// ---------------- CSR build ----------------
__global__ void hist_kernel(const int* __restrict__ dst, int* __restrict__ cnt) {
    int e = blockIdx.x * blockDim.x + threadIdx.x;
    if (e < N_EDGES) atomicAdd(&cnt[dst[e]], 1);
}

__global__ void scanA_kernel(const int* __restrict__ cnt, int* __restrict__ texcl,
                             int* __restrict__ bsum) {
    __shared__ int sh[SCAN_B];
    int tid = threadIdx.x;
    int i = blockIdx.x * SCAN_B + tid;
    int v = (i < N_NODES) ? cnt[i] : 0;
    sh[tid] = v;
    __syncthreads();
    for (int off = 1; off < SCAN_B; off <<= 1) {
        int t = (tid >= off) ? sh[tid - off] : 0;
        __syncthreads();
        sh[tid] += t;
        __syncthreads();
    }
    if (i < N_NODES) texcl[i] = sh[tid] - v;
    if (tid == SCAN_B - 1) bsum[blockIdx.x] = sh[tid];
}

__global__ void scanB_kernel(const int* __restrict__ bsum, int* __restrict__ bexcl, int nb) {
    __shared__ int sh[SCAN_B];
    int tid = threadIdx.x;
    int v = (tid < nb) ? bsum[tid] : 0;
    sh[tid] = v;
    __syncthreads();
    for (int off = 1; off < SCAN_B; off <<= 1) {
        int t = (tid >= off) ? sh[tid - off] : 0;
        __syncthreads();
        sh[tid] += t;
        __syncthreads();
    }
    if (tid < nb) bexcl[tid] = sh[tid] - v;
}

__global__ void scanC_kernel(const int* __restrict__ texcl, const int* __restrict__ bexcl,
                             int* __restrict__ row) {
    int i = blockIdx.x * blockDim.x + threadIdx.x;
    if (i < N_NODES) row[i] = texcl[i] + bexcl[i >> 8];
    if (blockIdx.x == 0 && threadIdx.x == 0) row[N_NODES] = N_EDGES;
}

__global__ void fill_kernel(const int* __restrict__ src, const int* __restrict__ dst,
                            const int* __restrict__ row, int* __restrict__ fc,
                            int* __restrict__ perm_src) {
    int e = blockIdx.x * blockDim.x + threadIdx.x;
    if (e >= N_EDGES) return;
    int d = dst[e];
    int p = row[d] + atomicAdd(&fc[d], 1);
    perm_src[p] = src[e];
}

// ---------------- layer 1 GEMM + fused attn coefficients ----------------
__global__ __launch_bounds__(256) void gemm1_kernel(const float* __restrict__ X,
                                                    const float* __restrict__ W1,
                                                    const float* __restrict__ al,
                                                    const float* __restrict__ ar,
                                                    float* __restrict__ feat1,
                                                    float* __restrict__ el1,
                                                    float* __restrict__ er1) {
    __shared__ float xs[IN_DIM * XS_STRIDE];   // [k][i]
    int n0 = blockIdx.x * NB1;
    int tid = threadIdx.x;
    for (int t = tid; t < NB1 * IN_DIM; t += 256) {
        int i = t >> 7, k = t & (IN_DIM - 1);
        xs[k * XS_STRIDE + i] = (n0 + i < N_NODES) ? X[(size_t)(n0 + i) * IN_DIM + k] : 0.f;
    }
    __syncthreads();
    float acc[NB1];
#pragma unroll
    for (int i = 0; i < NB1; ++i) acc[i] = 0.f;
#pragma unroll 2
    for (int k = 0; k < IN_DIM; ++k) {
        float wv = W1[k * L1_OUT + tid];
        const float4* x4 = (const float4*)&xs[k * XS_STRIDE];
#pragma unroll
        for (int q = 0; q < NB1 / 4; ++q) {
            float4 xv = x4[q];
            acc[q * 4 + 0] += xv.x * wv;
            acc[q * 4 + 1] += xv.y * wv;
            acc[q * 4 + 2] += xv.z * wv;
            acc[q * 4 + 3] += xv.w * wv;
        }
    }
    int h = tid >> 6;
    float al_c = al[tid], ar_c = ar[tid];
#pragma unroll
    for (int i = 0; i < NB1; ++i) {
        if (n0 + i < N_NODES) feat1[(size_t)(n0 + i) * L1_OUT + tid] = acc[i];
    }
#pragma unroll
    for (int i = 0; i < NB1; ++i) {
        float l = acc[i] * al_c, r = acc[i] * ar_c;
#pragma unroll
        for (int off = 1; off < 64; off <<= 1) {
            l += __shfl_xor(l, off, 64);
            r += __shfl_xor(r, off, 64);
        }
        if ((tid & 63) == 0 && n0 + i < N_NODES) {
            el1[(n0 + i) * HEADS + h] = l;
            er1[(n0 + i) * HEADS + h] = r;
        }
    }
}

// ---------------- layer 1 fused softmax + gather ----------------
__global__ __launch_bounds__(256) void gather1_kernel(const int* __restrict__ row,
                                                      const int* __restrict__ perm_src,
                                                      const float* __restrict__ el1,
                                                      const float* __restrict__ er1,
                                                      const float* __restrict__ feat1,
                                                      float* __restrict__ rst1) {
    __shared__ int psrc[DCHUNK];
    __shared__ float alds[DCHUNK * 5];     // [j][h], stride 5 -> conflict-free writes
    __shared__ float4 comb[4][64];
    int d = blockIdx.x;
    int tid = threadIdx.x;
    int w = tid >> 6, lane = tid & 63;
    int base = row[d], deg = row[d + 1] - base;
    float4* out4 = (float4*)&rst1[(size_t)d * L1_OUT];
    if (deg == 0) {
        if (tid < 64) out4[tid] = float4{0.f, 0.f, 0.f, 0.f};
        return;
    }
    if (deg <= DCHUNK) {
        if (tid < deg) psrc[tid] = perm_src[base + tid];
        __syncthreads();
        // scores: wave w == head w; lanes cover edges lane, lane+64
        float er_d = er1[d * HEADS + w];
        float s0 = -1e30f, s1 = -1e30f;
        if (lane < deg) s0 = leaky(el1[psrc[lane] * HEADS + w] + er_d);
        if (lane + 64 < deg) s1 = leaky(el1[psrc[lane + 64] * HEADS + w] + er_d);
        float m = fmaxf(s0, s1);
#pragma unroll
        for (int off = 1; off < 64; off <<= 1) m = fmaxf(m, __shfl_xor(m, off, 64));
        float e0 = (lane < deg) ? __expf(s0 - m) : 0.f;
        float e1 = (lane + 64 < deg) ? __expf(s1 - m) : 0.f;
        float ss = e0 + e1;
#pragma unroll
        for (int off = 1; off < 64; off <<= 1) ss += __shfl_xor(ss, off, 64);
        float inv = 1.f / ss;
        if (lane < deg) alds[lane * 5 + w] = e0 * inv;
        if (lane + 64 < deg) alds[(lane + 64) * 5 + w] = e1 * inv;
        __syncthreads();
        // accumulate: lane covers channels [lane*4, lane*4+4); wave w owns edges j==w mod 4
        int hh = lane >> 4;
        const float4* f4 = (const float4*)feat1;
        float4 a0 = {0.f, 0.f, 0.f, 0.f}, a1 = {0.f, 0.f, 0.f, 0.f};
        int j = w;
        for (; j + 4 < deg; j += 8) {
            int sA = psrc[j], sB = psrc[j + 4];
            float wA = alds[j * 5 + hh], wB = alds[(j + 4) * 5 + hh];
            float4 fA = f4[(size_t)sA * 64 + lane];
            float4 fB = f4[(size_t)sB * 64 + lane];
            a0.x += wA * fA.x; a0.y += wA * fA.y; a0.z += wA * fA.z; a0.w += wA * fA.w;
            a1.x += wB * fB.x; a1.y += wB * fB.y; a1.z += wB * fB.z; a1.w += wB * fB.w;
        }
        if (j < deg) {
            int sA = psrc[j];
            float wA = alds[j * 5 + hh];
            float4 fA = f4[(size_t)sA * 64 + lane];
            a0.x += wA * fA.x; a0.y += wA * fA.y; a0.z += wA * fA.z; a0.w += wA * fA.w;
        }
        a0.x += a1.x; a0.y += a1.y; a0.z += a1.z; a0.w += a1.w;
        comb[w][lane] = a0;
        __syncthreads();
        if (w == 0) {
            float4 c0 = comb[0][lane], c1 = comb[1][lane], c2 = comb[2][lane], c3 = comb[3][lane];
            float4 r;
            r.x = c0.x + c1.x + c2.x + c3.x;
            r.y = c0.y + c1.y + c2.y + c3.y;
            r.z = c0.z + c1.z + c2.z + c3.z;
            r.w = c0.w + c1.w + c2.w + c3.w;
            out4[lane] = r;
        }
    } else {
        // generic fallback (deg > DCHUNK): statistically never hit, required for correctness
        int h = w;
        float er_d = er1[d * HEADS + h];
        float m = -1e30f;
        for (int j = lane; j < deg; j += 64) {
            int s = perm_src[base + j];
            m = fmaxf(m, leaky(el1[s * HEADS + h] + er_d));
        }
#pragma unroll
        for (int off = 1; off < 64; off <<= 1) m = fmaxf(m, __shfl_xor(m, off, 64));
        float ss = 0.f;
        for (int j = lane; j < deg; j += 64) {
            int s = perm_src[base + j];
            ss += __expf(leaky(el1[s * HEADS + h] + er_d) - m);
        }
#pragma unroll
        for (int off = 1; off < 64; off <<= 1) ss += __shfl_xor(ss, off, 64);
        float inv = 1.f / ss;
        float acc = 0.f;
        for (int j = 0; j < deg; ++j) {
            int s = perm_src[base + j];
            float a = __expf(leaky(el1[s * HEADS + h] + er_d) - m) * inv;
            acc += a * feat1[(size_t)s * L1_OUT + tid];
        }
        rst1[(size_t)d * L1_OUT + tid] = acc;
    }
}

// ---------------- layer 2 GEMM + fused attn coefficients ----------------
__global__ __launch_bounds__(256) void gemm2_kernel(const float* __restrict__ rst1,
                                                    const float* __restrict__ b1,
                                                    const float* __restrict__ W2,
                                                    const float* __restrict__ al2,
                                                    const float* __restrict__ ar2,
                                                    float* __restrict__ feat2,
                                                    float* __restrict__ el2,
                                                    float* __restrict__ er2) {
    __shared__ float rs[L1_OUT * RS_STRIDE];   // [k][i]  36.9 KB
    int n0 = blockIdx.x * NB2;
    int tid = threadIdx.x;
    for (int t = tid; t < NB2 * L1_OUT; t += 256) {
        int i = t >> 8, k = t & (L1_OUT - 1);
        rs[k * RS_STRIDE + i] =
            (n0 + i < N_NODES) ? rst1[(size_t)(n0 + i) * L1_OUT + k] + b1[k] : 0.f;
    }
    __syncthreads();
    int c = tid & 63, g = tid >> 6;   // wave g handles nodes g*8..g*8+7
    float acc[8];
#pragma unroll
    for (int u = 0; u < 8; ++u) acc[u] = 0.f;
#pragma unroll 2
    for (int k = 0; k < L1_OUT; ++k) {
        float wv = W2[k * OUT_DIM + c];
        const float4* x4 = (const float4*)&rs[k * RS_STRIDE];
        float4 xa = x4[g * 2], xb = x4[g * 2 + 1];
        acc[0] += xa.x * wv; acc[1] += xa.y * wv; acc[2] += xa.z * wv; acc[3] += xa.w * wv;
        acc[4] += xb.x * wv; acc[5] += xb.y * wv; acc[6] += xb.z * wv; acc[7] += xb.w * wv;
    }
    float al_c = al2[c], ar_c = ar2[c];
#pragma unroll
    for (int u = 0; u < 8; ++u) {
        int n = n0 + g * 8 + u;
        if (n < N_NODES) feat2[(size_t)n * OUT_DIM + c] = acc[u];
        float l = acc[u] * al_c, r = acc[u] * ar_c;
#pragma unroll
        for (int off = 1; off < 64; off <<= 1) {
            l += __shfl_xor(l, off, 64);
            r += __shfl_xor(r, off, 64);
        }
        if (c == 0 && n < N_NODES) {
            el2[n] = l;
            er2[n] = r;
        }
    }
}

// ---------------- layer 2 fused softmax + gather (+bias) ----------------
__global__ __launch_bounds__(256) void gather2_kernel(const int* __restrict__ row,
                                                      const int* __restrict__ perm_src,
                                                      const float* __restrict__ el2,
                                                      const float* __restrict__ er2,
                                                      const float* __restrict__ feat2,
                                                      const float* __restrict__ b2,
                                                      float* __restrict__ out) {
    __shared__ int psrc[DCHUNK];
    __shared__ float alds[DCHUNK];
    __shared__ float comb[4][64];
    int d = blockIdx.x;
    int tid = threadIdx.x;
    int w = tid >> 6, lane = tid & 63;
    int base = row[d], deg = row[d + 1] - base;
    if (deg == 0) {
        if (tid < 64) out[(size_t)d * OUT_DIM + tid] = b2[tid];
        return;
    }
    if (deg <= DCHUNK) {
        if (tid < deg) psrc[tid] = perm_src[base + tid];
        __syncthreads();
        if (w == 0) {
            float er_d = er2[d];
            float s0 = -1e30f, s1 = -1e30f;
            if (lane < deg) s0 = leaky(el2[psrc[lane]] + er_d);
            if (lane + 64 < deg) s1 = leaky(el2[psrc[lane + 64]] + er_d);
            float m = fmaxf(s0, s1);
#pragma unroll
            for (int off = 1; off < 64; off <<= 1) m = fmaxf(m, __shfl_xor(m, off, 64));
            float e0 = (lane < deg) ? __expf(s0 - m) : 0.f;
            float e1 = (lane + 64 < deg) ? __expf(s1 - m) : 0.f;
            float ss = e0 + e1;
#pragma unroll
            for (int off = 1; off < 64; off <<= 1) ss += __shfl_xor(ss, off, 64);
            float inv = 1.f / ss;
            if (lane < deg) alds[lane] = e0 * inv;
            if (lane + 64 < deg) alds[lane + 64] = e1 * inv;
        }
        __syncthreads();
        float a0 = 0.f, a1 = 0.f;
        int j = w;
        for (; j + 4 < deg; j += 8) {
            int sA = psrc[j], sB = psrc[j + 4];
            float wA = alds[j], wB = alds[j + 4];
            a0 += wA * feat2[(size_t)sA * OUT_DIM + lane];
            a1 += wB * feat2[(size_t)sB * OUT_DIM + lane];
        }
        if (j < deg) a0 += alds[j] * feat2[(size_t)psrc[j] * OUT_DIM + lane];
        comb[w][lane] = a0 + a1;
        __syncthreads();
        if (w == 0)
            out[(size_t)d * OUT_DIM + lane] =
                comb[0][lane] + comb[1][lane] + comb[2][lane] + comb[3][lane] + b2[lane];
    } else {
        // generic fallback
        float er_d = er2[d];
        float m = -1e30f;
        for (int j = tid; j < deg; j += 256) {
            m = fmaxf(m, leaky(el2[perm_src[base + j]] + er_d));
        }
        __shared__ float red[4];
#pragma unroll
        for (int off = 1; off < 64; off <<= 1) m = fmaxf(m, __shfl_xor(m, off, 64));
        if (lane == 0) red[w] = m;
        __syncthreads();
        m = fmaxf(fmaxf(red[0], red[1]), fmaxf(red[2], red[3]));
        float ss = 0.f;
        for (int j = tid; j < deg; j += 256) {
            ss += __expf(leaky(el2[perm_src[base + j]] + er_d) - m);
        }
#pragma unroll
        for (int off = 1; off < 64; off <<= 1) ss += __shfl_xor(ss, off, 64);
        __syncthreads();
        if (lane == 0) red[w] = ss;
        __syncthreads();
        ss = red[0] + red[1] + red[2] + red[3];
        float inv = 1.f / ss;
        if (tid < 64) {
            float acc = 0.f;
            for (int j = 0; j < deg; ++j) {
                int s = perm_src[base + j];
                float a = __expf(leaky(el2[s] + er_d) - m) * inv;
                acc += a * feat2[(size_t)s * OUT_DIM + tid];
            }
            out[(size_t)d * OUT_DIM + tid] = acc + b2[tid];
        }
    }
}

extern "C" void kernel_launch(void* const* d_in, const int* in_sizes, int n_in,
                              void* d_out, int out_size, void* d_ws, size_t ws_size,
                              hipStream_t stream) {
    const float* features = (const float*)d_in[0];
    const int* src = (const int*)d_in[1];
    const int* dst = (const int*)d_in[2];
    const float* W1 = (const float*)d_in[3];
    const float* al1 = (const float*)d_in[4];
    const float* ar1 = (const float*)d_in[5];
    const float* b1 = (const float*)d_in[6];
    const float* W2 = (const float*)d_in[7];
    const float* al2 = (const float*)d_in[8];
    const float* ar2 = (const float*)d_in[9];
    const float* b2 = (const float*)d_in[10];
    float* out = (float*)d_out;

    // workspace layout
    float* ws = (float*)d_ws;
    float* feat1 = ws;                               // N*256
    float* rst1 = feat1 + (size_t)N_NODES * L1_OUT;  // N*256
    float* feat2 = rst1 + (size_t)N_NODES * L1_OUT;  // N*64
    float* el1 = feat2 + (size_t)N_NODES * OUT_DIM;  // N*4
    float* er1 = el1 + N_NODES * HEADS;              // N*4
    float* el2 = er1 + N_NODES * HEADS;              // N
    float* er2 = el2 + N_NODES;                      // N
    int* cnt = (int*)(er2 + N_NODES);                // N
    int* fc = cnt + N_NODES;                         // N
    int* texcl = fc + N_NODES;                       // N
    int* bsum = texcl + N_NODES;                     // 256
    int* bexcl = bsum + 256;                         // 256
    int* row = bexcl + 256;                          // N+1
    int* perm_src = row + N_NODES + 1;               // E

    const int nscan = (N_NODES + SCAN_B - 1) / SCAN_B;   // 196

    hipMemsetAsync(cnt, 0, (size_t)N_NODES * sizeof(int), stream);
    hipMemsetAsync(fc, 0, (size_t)N_NODES * sizeof(int), stream);

    // CSR build
    hist_kernel<<<(N_EDGES + 255) / 256, 256, 0, stream>>>(dst, cnt);
    scanA_kernel<<<nscan, SCAN_B, 0, stream>>>(cnt, texcl, bsum);
    scanB_kernel<<<1, SCAN_B, 0, stream>>>(bsum, bexcl, nscan);
    scanC_kernel<<<(N_NODES + 255) / 256, 256, 0, stream>>>(texcl, bexcl, row);
    fill_kernel<<<(N_EDGES + 255) / 256, 256, 0, stream>>>(src, dst, row, fc, perm_src);

    // layer 1
    gemm1_kernel<<<(N_NODES + NB1 - 1) / NB1, 256, 0, stream>>>(features, W1, al1, ar1,
                                                                feat1, el1, er1);
    gather1_kernel<<<N_NODES, 256, 0, stream>>>(row, perm_src, el1, er1, feat1, rst1);

    // layer 2
    gemm2_kernel<<<(N_NODES + NB2 - 1) / NB2, 256, 0, stream>>>(rst1, b1, W2, al2, ar2,
                                                                feat2, el2, er2);
    gather2_kernel<<<N_NODES, 256, 0, stream>>>(row, perm_src, el2, er2, feat2, b2, out);
}

// Round 4
// 253.135 us; speedup vs baseline: 1.4630x; 1.4630x over previous
//
#include <hip/hip_runtime.h>
#include <hip/hip_bf16.h>

#define N_NODES 50000
#define N_EDGES 400000
#define IN_DIM 128
#define HID 64
#define HEADS 4
#define L1_OUT (HEADS * HID)   // 256
#define OUT_DIM 64
#define NEG_SLOPE 0.2f
#define SCAN_B 256
#define DCHUNK 128

typedef short bf16x8 __attribute__((ext_vector_type(8)));
typedef float f32x4 __attribute__((ext_vector_type(4)));

__device__ __forceinline__ float leaky(float x) { return x > 0.f ? x : NEG_SLOPE * x; }

// RNE float->bf16 bits, bf16 bits->float
__device__ __forceinline__ unsigned short bfh(float x) {
    unsigned u = __float_as_uint(x);
    return (unsigned short)((u + 0x7fffu + ((u >> 16) & 1u)) >> 16);
}
__device__ __forceinline__ float fb(unsigned short h) {
    return __uint_as_float(((unsigned)h) << 16);
}

// ---------------- CSR build ----------------
__global__ void hist_kernel(const int* __restrict__ dst, int* __restrict__ cnt) {
    int e = blockIdx.x * blockDim.x + threadIdx.x;
    if (e < N_EDGES) atomicAdd(&cnt[dst[e]], 1);
}

__global__ void scanA_kernel(const int* __restrict__ cnt, int* __restrict__ texcl,
                             int* __restrict__ bsum) {
    __shared__ int sh[SCAN_B];
    int tid = threadIdx.x;
    int i = blockIdx.x * SCAN_B + tid;
    int v = (i < N_NODES) ? cnt[i] : 0;
    sh[tid] = v;
    __syncthreads();
    for (int off = 1; off < SCAN_B; off <<= 1) {
        int t = (tid >= off) ? sh[tid - off] : 0;
        __syncthreads();
        sh[tid] += t;
        __syncthreads();
    }
    if (i < N_NODES) texcl[i] = sh[tid] - v;
    if (tid == SCAN_B - 1) bsum[blockIdx.x] = sh[tid];
}

__global__ void scanB_kernel(const int* __restrict__ bsum, int* __restrict__ bexcl, int nb) {
    __shared__ int sh[SCAN_B];
    int tid = threadIdx.x;
    int v = (tid < nb) ? bsum[tid] : 0;
    sh[tid] = v;
    __syncthreads();
    for (int off = 1; off < SCAN_B; off <<= 1) {
        int t = (tid >= off) ? sh[tid - off] : 0;
        __syncthreads();
        sh[tid] += t;
        __syncthreads();
    }
    if (tid < nb) bexcl[tid] = sh[tid] - v;
}

__global__ void scanC_kernel(const int* __restrict__ texcl, const int* __restrict__ bexcl,
                             int* __restrict__ row) {
    int i = blockIdx.x * blockDim.x + threadIdx.x;
    if (i < N_NODES) row[i] = texcl[i] + bexcl[i >> 8];
    if (blockIdx.x == 0 && threadIdx.x == 0) row[N_NODES] = N_EDGES;
}

__global__ void fill_kernel(const int* __restrict__ src, const int* __restrict__ dst,
                            const int* __restrict__ row, int* __restrict__ fc,
                            int* __restrict__ perm_src) {
    int e = blockIdx.x * blockDim.x + threadIdx.x;
    if (e >= N_EDGES) return;
    int d = dst[e];
    int p = row[d] + atomicAdd(&fc[d], 1);
    perm_src[p] = src[e];
}

// ---------------- W fragment prep: hi/lo bf16 in MFMA B-fragment order ----------------
// W1frag: [ntile 16][kstep 4][lane 64][j 8]; elem = W1[kstep*32+(lane>>4)*8+j][ntile*16+(lane&15)]
// W2frag: [ntile 4][kstep 8][lane 64][j 8];  elem = W2[kstep*32+(lane>>4)*8+j][ntile*16+(lane&15)]
__global__ void wprep_kernel(const float* __restrict__ W1, const float* __restrict__ W2,
                             unsigned short* __restrict__ W1fh, unsigned short* __restrict__ W1fl,
                             unsigned short* __restrict__ W2fh, unsigned short* __restrict__ W2fl) {
    int s = blockIdx.x * 256 + threadIdx.x;
    if (s < 4096) {
        int lane = s & 63, ks = (s >> 6) & 3, ntile = s >> 8;
        int n = ntile * 16 + (lane & 15);
        int kb = ks * 32 + (lane >> 4) * 8;
#pragma unroll
        for (int j = 0; j < 8; ++j) {
            float w = W1[(kb + j) * L1_OUT + n];
            unsigned short h = bfh(w);
            W1fh[s * 8 + j] = h;
            W1fl[s * 8 + j] = bfh(w - fb(h));
        }
    } else if (s < 6144) {
        int s2 = s - 4096;
        int lane = s2 & 63, ks = (s2 >> 6) & 7, ntile = s2 >> 9;
        int n = ntile * 16 + (lane & 15);
        int kb = ks * 32 + (lane >> 4) * 8;
#pragma unroll
        for (int j = 0; j < 8; ++j) {
            float w = W2[(kb + j) * OUT_DIM + n];
            unsigned short h = bfh(w);
            W2fh[s2 * 8 + j] = h;
            W2fl[s2 * 8 + j] = bfh(w - fb(h));
        }
    }
}

// ---------------- gemm1 (MFMA): feat1b = bf16(X @ W1), M-tile 64, N=256, 8 waves ----------------
__global__ __launch_bounds__(512) void gemm1_kernel(const float* __restrict__ X,
                                                    const unsigned short* __restrict__ W1fh,
                                                    const unsigned short* __restrict__ W1fl,
                                                    unsigned short* __restrict__ feat1b) {
    __shared__ unsigned short Ah[4 * 4 * 64 * 8];   // [mfrag][kstep][lane][j]
    __shared__ unsigned short Al[4 * 4 * 64 * 8];
    int t = threadIdx.x;
    int m0 = blockIdx.x * 64;

    // stage X tile (64x128 fp32) -> hi/lo bf16 fragment order
    {
        int m = t >> 3;
        int k0 = (t & 7) * 16;
        int mfrag = m >> 4, mrow = m & 15;
        bool valid = (m0 + m) < N_NODES;
        const float4* xr = (const float4*)&X[(size_t)(m0 + m) * IN_DIM];
#pragma unroll
        for (int g = 0; g < 4; ++g) {
            int k = k0 + g * 4;
            float4 v = valid ? xr[k >> 2] : float4{0.f, 0.f, 0.f, 0.f};
            int kstep = k >> 5, kk = k & 31;
            int lane = mrow + 16 * (kk >> 3);
            int j0 = kk & 7;
            int base = ((mfrag * 4 + kstep) * 64 + lane) * 8 + j0;
            unsigned short h0 = bfh(v.x), h1 = bfh(v.y), h2 = bfh(v.z), h3 = bfh(v.w);
            *(ushort4*)&Ah[base] = make_ushort4(h0, h1, h2, h3);
            *(ushort4*)&Al[base] = make_ushort4(bfh(v.x - fb(h0)), bfh(v.y - fb(h1)),
                                                bfh(v.z - fb(h2)), bfh(v.w - fb(h3)));
        }
    }
    __syncthreads();

    int w = t >> 6, lane = t & 63;
    int wr = w >> 2, wc = w & 3;   // wave tile: rows wr*32..+31, cols wc*64..+63
    f32x4 acc[2][4];
#pragma unroll
    for (int mi = 0; mi < 2; ++mi)
#pragma unroll
        for (int nf = 0; nf < 4; ++nf) acc[mi][nf] = f32x4{0.f, 0.f, 0.f, 0.f};

#pragma unroll
    for (int kstep = 0; kstep < 4; ++kstep) {
        bf16x8 a_h[2], a_l[2];
#pragma unroll
        for (int mi = 0; mi < 2; ++mi) {
            int slot = (((wr * 2 + mi) * 4 + kstep) * 64 + lane) * 8;
            a_h[mi] = *(const bf16x8*)&Ah[slot];
            a_l[mi] = *(const bf16x8*)&Al[slot];
        }
#pragma unroll
        for (int nf = 0; nf < 4; ++nf) {
            int slot = (((wc * 4 + nf) * 4 + kstep) * 64 + lane) * 8;
            bf16x8 b_h = *(const bf16x8*)&W1fh[slot];
            bf16x8 b_l = *(const bf16x8*)&W1fl[slot];
#pragma unroll
            for (int mi = 0; mi < 2; ++mi) {
                acc[mi][nf] = __builtin_amdgcn_mfma_f32_16x16x32_bf16(a_h[mi], b_h, acc[mi][nf], 0, 0, 0);
                acc[mi][nf] = __builtin_amdgcn_mfma_f32_16x16x32_bf16(a_h[mi], b_l, acc[mi][nf], 0, 0, 0);
                acc[mi][nf] = __builtin_amdgcn_mfma_f32_16x16x32_bf16(a_l[mi], b_h, acc[mi][nf], 0, 0, 0);
            }
        }
    }

    // epilogue: D[row=(l>>4)*4+j][col=l&15]
    int fq = lane >> 4, fr = lane & 15;
#pragma unroll
    for (int mi = 0; mi < 2; ++mi) {
#pragma unroll
        for (int j = 0; j < 4; ++j) {
            int r = m0 + wr * 32 + mi * 16 + fq * 4 + j;
            if (r >= N_NODES) continue;
#pragma unroll
            for (int nf = 0; nf < 4; ++nf) {
                int c = wc * 64 + nf * 16 + fr;
                feat1b[(size_t)r * L1_OUT + c] = bfh(acc[mi][nf][j]);
            }
        }
    }
}

// ---------------- attn1: el/er from bf16 feat1 (4 nodes/block) ----------------
__global__ __launch_bounds__(256) void attn1_kernel(const unsigned short* __restrict__ feat1b,
                                                    const float* __restrict__ al,
                                                    const float* __restrict__ ar,
                                                    float* __restrict__ el1,
                                                    float* __restrict__ er1) {
    int t = threadIdx.x, w = t >> 6, lane = t & 63;
    int n = blockIdx.x * 4 + w;
    ushort4 v = *(const ushort4*)&feat1b[(size_t)n * L1_OUT + lane * 4];
    float4 a4 = *(const float4*)&al[lane * 4];
    float4 r4 = *(const float4*)&ar[lane * 4];
    float f0 = fb(v.x), f1 = fb(v.y), f2 = fb(v.z), f3 = fb(v.w);
    float l = f0 * a4.x + f1 * a4.y + f2 * a4.z + f3 * a4.w;
    float r = f0 * r4.x + f1 * r4.y + f2 * r4.z + f3 * r4.w;
#pragma unroll
    for (int off = 1; off < 16; off <<= 1) {
        l += __shfl_xor(l, off, 64);
        r += __shfl_xor(r, off, 64);
    }
    if ((lane & 15) == 0) {
        int h = lane >> 4;
        el1[n * HEADS + h] = l;
        er1[n * HEADS + h] = r;
    }
}

// ---------------- gather1: fused softmax + aggregate (bf16 feats) ----------------
__global__ __launch_bounds__(256) void gather1_kernel(const int* __restrict__ row,
                                                      const int* __restrict__ perm_src,
                                                      const float* __restrict__ el1,
                                                      const float* __restrict__ er1,
                                                      const unsigned short* __restrict__ feat1b,
                                                      float* __restrict__ rst1) {
    __shared__ int psrc[DCHUNK];
    __shared__ float alds[DCHUNK * 5];
    __shared__ float4 comb[4][64];
    int d = blockIdx.x;
    int tid = threadIdx.x;
    int w = tid >> 6, lane = tid & 63;
    int base = row[d], deg = row[d + 1] - base;
    float4* out4 = (float4*)&rst1[(size_t)d * L1_OUT];
    if (deg == 0) {
        if (tid < 64) out4[tid] = float4{0.f, 0.f, 0.f, 0.f};
        return;
    }
    if (deg <= DCHUNK) {
        if (tid < deg) psrc[tid] = perm_src[base + tid];
        __syncthreads();
        float er_d = er1[d * HEADS + w];
        float s0 = -1e30f, s1 = -1e30f;
        if (lane < deg) s0 = leaky(el1[psrc[lane] * HEADS + w] + er_d);
        if (lane + 64 < deg) s1 = leaky(el1[psrc[lane + 64] * HEADS + w] + er_d);
        float m = fmaxf(s0, s1);
#pragma unroll
        for (int off = 1; off < 64; off <<= 1) m = fmaxf(m, __shfl_xor(m, off, 64));
        float e0 = (lane < deg) ? __expf(s0 - m) : 0.f;
        float e1 = (lane + 64 < deg) ? __expf(s1 - m) : 0.f;
        float ss = e0 + e1;
#pragma unroll
        for (int off = 1; off < 64; off <<= 1) ss += __shfl_xor(ss, off, 64);
        float inv = 1.f / ss;
        if (lane < deg) alds[lane * 5 + w] = e0 * inv;
        if (lane + 64 < deg) alds[(lane + 64) * 5 + w] = e1 * inv;
        __syncthreads();
        int hh = lane >> 4;
        const ushort4* f4 = (const ushort4*)feat1b;
        float4 a0 = {0.f, 0.f, 0.f, 0.f}, a1 = {0.f, 0.f, 0.f, 0.f};
        int j = w;
        for (; j + 4 < deg; j += 8) {
            int sA = psrc[j], sB = psrc[j + 4];
            float wA = alds[j * 5 + hh], wB = alds[(j + 4) * 5 + hh];
            ushort4 fA = f4[(size_t)sA * 64 + lane];
            ushort4 fB = f4[(size_t)sB * 64 + lane];
            a0.x += wA * fb(fA.x); a0.y += wA * fb(fA.y); a0.z += wA * fb(fA.z); a0.w += wA * fb(fA.w);
            a1.x += wB * fb(fB.x); a1.y += wB * fb(fB.y); a1.z += wB * fb(fB.z); a1.w += wB * fb(fB.w);
        }
        if (j < deg) {
            int sA = psrc[j];
            float wA = alds[j * 5 + hh];
            ushort4 fA = f4[(size_t)sA * 64 + lane];
            a0.x += wA * fb(fA.x); a0.y += wA * fb(fA.y); a0.z += wA * fb(fA.z); a0.w += wA * fb(fA.w);
        }
        a0.x += a1.x; a0.y += a1.y; a0.z += a1.z; a0.w += a1.w;
        comb[w][lane] = a0;
        __syncthreads();
        if (w == 0) {
            float4 c0 = comb[0][lane], c1 = comb[1][lane], c2 = comb[2][lane], c3 = comb[3][lane];
            float4 r;
            r.x = c0.x + c1.x + c2.x + c3.x;
            r.y = c0.y + c1.y + c2.y + c3.y;
            r.z = c0.z + c1.z + c2.z + c3.z;
            r.w = c0.w + c1.w + c2.w + c3.w;
            out4[lane] = r;
        }
    } else {
        // generic fallback (deg > DCHUNK)
        int h = w;
        float er_d = er1[d * HEADS + h];
        float m = -1e30f;
        for (int j = lane; j < deg; j += 64) {
            int s = perm_src[base + j];
            m = fmaxf(m, leaky(el1[s * HEADS + h] + er_d));
        }
#pragma unroll
        for (int off = 1; off < 64; off <<= 1) m = fmaxf(m, __shfl_xor(m, off, 64));
        float ss = 0.f;
        for (int j = lane; j < deg; j += 64) {
            int s = perm_src[base + j];
            ss += __expf(leaky(el1[s * HEADS + h] + er_d) - m);
        }
#pragma unroll
        for (int off = 1; off < 64; off <<= 1) ss += __shfl_xor(ss, off, 64);
        float inv = 1.f / ss;
        float acc = 0.f;
        for (int j = 0; j < deg; ++j) {
            int s = perm_src[base + j];
            float a = __expf(leaky(el1[s * HEADS + h] + er_d) - m) * inv;
            acc += a * fb(feat1b[(size_t)s * L1_OUT + tid]);
        }
        rst1[(size_t)d * L1_OUT + tid] = acc;
    }
}

// ---------------- gemm2 (MFMA): feat2b = bf16((rst1+b1) @ W2), M-tile 32, N=64, 4 waves ----------------
__global__ __launch_bounds__(256) void gemm2_kernel(const float* __restrict__ rst1,
                                                    const float* __restrict__ b1,
                                                    const unsigned short* __restrict__ W2fh,
                                                    const unsigned short* __restrict__ W2fl,
                                                    unsigned short* __restrict__ feat2b) {
    __shared__ unsigned short Ah[2 * 8 * 64 * 8];   // [mfrag][kstep][lane][j]
    __shared__ unsigned short Al[2 * 8 * 64 * 8];
    int t = threadIdx.x;
    int n0 = blockIdx.x * 32;

    // stage (rst1+b1) tile (32x256) -> hi/lo bf16 fragment order
    {
        int m = t >> 3;
        int kstep = t & 7;
        int mfrag = m >> 4, mrow = m & 15;
        bool valid = (n0 + m) < N_NODES;
        const float4* ar4 = (const float4*)&rst1[(size_t)(n0 + m) * L1_OUT];
        const float4* br4 = (const float4*)b1;
#pragma unroll
        for (int g = 0; g < 8; ++g) {
            int k = kstep * 32 + g * 4;
            float4 v = valid ? ar4[k >> 2] : float4{0.f, 0.f, 0.f, 0.f};
            float4 bb = br4[k >> 2];
            v.x += bb.x; v.y += bb.y; v.z += bb.z; v.w += bb.w;
            if (!valid) { v.x = 0.f; v.y = 0.f; v.z = 0.f; v.w = 0.f; }
            int lane = mrow + 16 * (g >> 1);
            int j0 = (g & 1) * 4;
            int base = ((mfrag * 8 + kstep) * 64 + lane) * 8 + j0;
            unsigned short h0 = bfh(v.x), h1 = bfh(v.y), h2 = bfh(v.z), h3 = bfh(v.w);
            *(ushort4*)&Ah[base] = make_ushort4(h0, h1, h2, h3);
            *(ushort4*)&Al[base] = make_ushort4(bfh(v.x - fb(h0)), bfh(v.y - fb(h1)),
                                                bfh(v.z - fb(h2)), bfh(v.w - fb(h3)));
        }
    }
    __syncthreads();

    int w = t >> 6, lane = t & 63;
    int mi = w >> 1, nh = w & 1;    // wave: m-frag mi (16 rows), n-frags nh*2..nh*2+1
    f32x4 acc[2];
    acc[0] = f32x4{0.f, 0.f, 0.f, 0.f};
    acc[1] = f32x4{0.f, 0.f, 0.f, 0.f};

#pragma unroll
    for (int ks = 0; ks < 8; ++ks) {
        int aslot = ((mi * 8 + ks) * 64 + lane) * 8;
        bf16x8 a_h = *(const bf16x8*)&Ah[aslot];
        bf16x8 a_l = *(const bf16x8*)&Al[aslot];
#pragma unroll
        for (int nf = 0; nf < 2; ++nf) {
            int ntile = nh * 2 + nf;
            int slot = ((ntile * 8 + ks) * 64 + lane) * 8;
            bf16x8 b_h = *(const bf16x8*)&W2fh[slot];
            bf16x8 b_l = *(const bf16x8*)&W2fl[slot];
            acc[nf] = __builtin_amdgcn_mfma_f32_16x16x32_bf16(a_h, b_h, acc[nf], 0, 0, 0);
            acc[nf] = __builtin_amdgcn_mfma_f32_16x16x32_bf16(a_h, b_l, acc[nf], 0, 0, 0);
            acc[nf] = __builtin_amdgcn_mfma_f32_16x16x32_bf16(a_l, b_h, acc[nf], 0, 0, 0);
        }
    }

    int fq = lane >> 4, fr = lane & 15;
#pragma unroll
    for (int j = 0; j < 4; ++j) {
        int r = n0 + mi * 16 + fq * 4 + j;
        if (r >= N_NODES) continue;
#pragma unroll
        for (int nf = 0; nf < 2; ++nf) {
            int c = (nh * 2 + nf) * 16 + fr;
            feat2b[(size_t)r * OUT_DIM + c] = bfh(acc[nf][j]);
        }
    }
}

// ---------------- attn2: el2/er2 from bf16 feat2 (16 nodes/block) ----------------
__global__ __launch_bounds__(256) void attn2_kernel(const unsigned short* __restrict__ feat2b,
                                                    const float* __restrict__ al2,
                                                    const float* __restrict__ ar2,
                                                    float* __restrict__ el2,
                                                    float* __restrict__ er2) {
    int t = threadIdx.x;
    int n = blockIdx.x * 16 + (t >> 4);
    int sub = t & 15;
    ushort4 v = *(const ushort4*)&feat2b[(size_t)n * OUT_DIM + sub * 4];
    float4 a4 = *(const float4*)&al2[sub * 4];
    float4 r4 = *(const float4*)&ar2[sub * 4];
    float f0 = fb(v.x), f1 = fb(v.y), f2 = fb(v.z), f3 = fb(v.w);
    float l = f0 * a4.x + f1 * a4.y + f2 * a4.z + f3 * a4.w;
    float r = f0 * r4.x + f1 * r4.y + f2 * r4.z + f3 * r4.w;
#pragma unroll
    for (int off = 1; off < 16; off <<= 1) {
        l += __shfl_xor(l, off, 64);
        r += __shfl_xor(r, off, 64);
    }
    if (sub == 0) {
        el2[n] = l;
        er2[n] = r;
    }
}

// ---------------- gather2: fused softmax + aggregate + bias (bf16 feats) ----------------
__global__ __launch_bounds__(256) void gather2_kernel(const int* __restrict__ row,
                                                      const int* __restrict__ perm_src,
                                                      const float* __restrict__ el2,
                                                      const float* __restrict__ er2,
                                                      const unsigned short* __restrict__ feat2b,
                                                      const float* __restrict__ b2,
                                                      float* __restrict__ out) {
    __shared__ int psrc[DCHUNK];
    __shared__ float alds[DCHUNK];
    __shared__ float comb[8][64];
    int d = blockIdx.x;
    int tid = threadIdx.x;
    int w = tid >> 6, lane = tid & 63;
    int base = row[d], deg = row[d + 1] - base;
    if (deg == 0) {
        if (tid < 64) out[(size_t)d * OUT_DIM + tid] = b2[tid];
        return;
    }
    if (deg <= DCHUNK) {
        if (tid < deg) psrc[tid] = perm_src[base + tid];
        __syncthreads();
        if (w == 0) {
            float er_d = er2[d];
            float s0 = -1e30f, s1 = -1e30f;
            if (lane < deg) s0 = leaky(el2[psrc[lane]] + er_d);
            if (lane + 64 < deg) s1 = leaky(el2[psrc[lane + 64]] + er_d);
            float m = fmaxf(s0, s1);
#pragma unroll
            for (int off = 1; off < 64; off <<= 1) m = fmaxf(m, __shfl_xor(m, off, 64));
            float e0 = (lane < deg) ? __expf(s0 - m) : 0.f;
            float e1 = (lane + 64 < deg) ? __expf(s1 - m) : 0.f;
            float ss = e0 + e1;
#pragma unroll
            for (int off = 1; off < 64; off <<= 1) ss += __shfl_xor(ss, off, 64);
            float inv = 1.f / ss;
            if (lane < deg) alds[lane] = e0 * inv;
            if (lane + 64 < deg) alds[lane + 64] = e1 * inv;
        }
        __syncthreads();
        int c2 = lane & 31, eo = lane >> 5;
        const ushort2* f2 = (const ushort2*)feat2b;
        float ax = 0.f, ay = 0.f;
        for (int j = w * 2 + eo; j < deg; j += 8) {
            int s = psrc[j];
            float a = alds[j];
            ushort2 v = f2[(size_t)s * 32 + c2];
            ax += a * fb(v.x);
            ay += a * fb(v.y);
        }
        int slot = w * 2 + eo;
        comb[slot][c2 * 2] = ax;
        comb[slot][c2 * 2 + 1] = ay;
        __syncthreads();
        if (tid < 64) {
            float s = comb[0][tid] + comb[1][tid] + comb[2][tid] + comb[3][tid] +
                      comb[4][tid] + comb[5][tid] + comb[6][tid] + comb[7][tid] + b2[tid];
            out[(size_t)d * OUT_DIM + tid] = s;
        }
    } else {
        // generic fallback
        float er_d = er2[d];
        float m = -1e30f;
        for (int j = tid; j < deg; j += 256) {
            m = fmaxf(m, leaky(el2[perm_src[base + j]] + er_d));
        }
        __shared__ float red[4];
#pragma unroll
        for (int off = 1; off < 64; off <<= 1) m = fmaxf(m, __shfl_xor(m, off, 64));
        if (lane == 0) red[w] = m;
        __syncthreads();
        m = fmaxf(fmaxf(red[0], red[1]), fmaxf(red[2], red[3]));
        float ss = 0.f;
        for (int j = tid; j < deg; j += 256) {
            ss += __expf(leaky(el2[perm_src[base + j]] + er_d) - m);
        }
#pragma unroll
        for (int off = 1; off < 64; off <<= 1) ss += __shfl_xor(ss, off, 64);
        __syncthreads();
        if (lane == 0) red[w] = ss;
        __syncthreads();
        ss = red[0] + red[1] + red[2] + red[3];
        float inv = 1.f / ss;
        if (tid < 64) {
            float acc = 0.f;
            for (int j = 0; j < deg; ++j) {
                int s = perm_src[base + j];
                float a = __expf(leaky(el2[s] + er_d) - m) * inv;
                acc += a * fb(feat2b[(size_t)s * OUT_DIM + tid]);
            }
            out[(size_t)d * OUT_DIM + tid] = acc + b2[tid];
        }
    }
}

extern "C" void kernel_launch(void* const* d_in, const int* in_sizes, int n_in,
                              void* d_out, int out_size, void* d_ws, size_t ws_size,
                              hipStream_t stream) {
    const float* features = (const float*)d_in[0];
    const int* src = (const int*)d_in[1];
    const int* dst = (const int*)d_in[2];
    const float* W1 = (const float*)d_in[3];
    const float* al1 = (const float*)d_in[4];
    const float* ar1 = (const float*)d_in[5];
    const float* b1 = (const float*)d_in[6];
    const float* W2 = (const float*)d_in[7];
    const float* al2 = (const float*)d_in[8];
    const float* ar2 = (const float*)d_in[9];
    const float* b2 = (const float*)d_in[10];
    float* out = (float*)d_out;

    // workspace layout
    float* ws = (float*)d_ws;
    float* rst1 = ws;                                          // N*256 f32
    float* el1 = rst1 + (size_t)N_NODES * L1_OUT;              // N*4
    float* er1 = el1 + N_NODES * HEADS;                        // N*4
    float* el2 = er1 + N_NODES * HEADS;                        // N
    float* er2 = el2 + N_NODES;                                // N
    unsigned short* feat1b = (unsigned short*)(er2 + N_NODES); // N*256 bf16
    unsigned short* feat2b = feat1b + (size_t)N_NODES * L1_OUT;// N*64 bf16
    unsigned short* W1fh = feat2b + (size_t)N_NODES * OUT_DIM; // 32768
    unsigned short* W1fl = W1fh + 32768;                       // 32768
    unsigned short* W2fh = W1fl + 32768;                       // 16384
    unsigned short* W2fl = W2fh + 16384;                       // 16384
    int* cnt = (int*)(W2fl + 16384);                           // N
    int* fc = cnt + N_NODES;                                   // N
    int* texcl = fc + N_NODES;                                 // N
    int* bsum = texcl + N_NODES;                               // 256
    int* bexcl = bsum + 256;                                   // 256
    int* row = bexcl + 256;                                    // N+1
    int* perm_src = row + N_NODES + 1;                         // E

    const int nscan = (N_NODES + SCAN_B - 1) / SCAN_B;   // 196

    hipMemsetAsync(cnt, 0, (size_t)2 * N_NODES * sizeof(int), stream);  // cnt + fc

    // CSR build
    hist_kernel<<<(N_EDGES + 255) / 256, 256, 0, stream>>>(dst, cnt);
    scanA_kernel<<<nscan, SCAN_B, 0, stream>>>(cnt, texcl, bsum);
    scanB_kernel<<<1, SCAN_B, 0, stream>>>(bsum, bexcl, nscan);
    scanC_kernel<<<(N_NODES + 255) / 256, 256, 0, stream>>>(texcl, bexcl, row);
    fill_kernel<<<(N_EDGES + 255) / 256, 256, 0, stream>>>(src, dst, row, fc, perm_src);

    // weight fragment prep
    wprep_kernel<<<24, 256, 0, stream>>>(W1, W2, W1fh, W1fl, W2fh, W2fl);

    // layer 1
    gemm1_kernel<<<(N_NODES + 63) / 64, 512, 0, stream>>>(features, W1fh, W1fl, feat1b);
    attn1_kernel<<<N_NODES / 4, 256, 0, stream>>>(feat1b, al1, ar1, el1, er1);
    gather1_kernel<<<N_NODES, 256, 0, stream>>>(row, perm_src, el1, er1, feat1b, rst1);

    // layer 2
    gemm2_kernel<<<(N_NODES + 31) / 32, 256, 0, stream>>>(rst1, b1, W2fh, W2fl, feat2b);
    attn2_kernel<<<N_NODES / 16, 256, 0, stream>>>(feat2b, al2, ar2, el2, er2);
    gather2_kernel<<<N_NODES, 256, 0, stream>>>(row, perm_src, el2, er2, feat2b, b2, out);
}

// Round 5
// 193.891 us; speedup vs baseline: 1.9100x; 1.3056x over previous
//
#include <hip/hip_runtime.h>
#include <hip/hip_bf16.h>

#define N_NODES 50000
#define N_EDGES 400000
#define IN_DIM 128
#define HID 64
#define HEADS 4
#define L1_OUT (HEADS * HID)   // 256
#define OUT_DIM 64
#define NEG_SLOPE 0.2f
#define SCAN_B 256
#define DCHUNK 128
#define HIST_B 1563            // ceil(400000/256)

typedef short bf16x8 __attribute__((ext_vector_type(8)));
typedef float f32x4 __attribute__((ext_vector_type(4)));

__device__ __forceinline__ float leaky(float x) { return x > 0.f ? x : NEG_SLOPE * x; }

// RNE float->bf16 bits, bf16 bits->float
__device__ __forceinline__ unsigned short bfh(float x) {
    unsigned u = __float_as_uint(x);
    return (unsigned short)((u + 0x7fffu + ((u >> 16) & 1u)) >> 16);
}
__device__ __forceinline__ float fb(unsigned short h) {
    return __uint_as_float(((unsigned)h) << 16);
}

// ---------------- CSR hist + W fragment prep (merged) ----------------
// W1frag: [ntile 16][kstep 4][lane 64][j 8]; elem = W1[kstep*32+(lane>>4)*8+j][ntile*16+(lane&15)]
// W2frag: [ntile 4][kstep 8][lane 64][j 8];  elem = W2[kstep*32+(lane>>4)*8+j][ntile*16+(lane&15)]
__global__ void hist_wprep_kernel(const int* __restrict__ dst, int* __restrict__ cnt,
                                  const float* __restrict__ W1, const float* __restrict__ W2,
                                  unsigned short* __restrict__ W1fh, unsigned short* __restrict__ W1fl,
                                  unsigned short* __restrict__ W2fh, unsigned short* __restrict__ W2fl) {
    int bid = blockIdx.x;
    if (bid < HIST_B) {
        int e = bid * 256 + threadIdx.x;
        if (e < N_EDGES) atomicAdd(&cnt[dst[e]], 1);
        return;
    }
    int s = (bid - HIST_B) * 256 + threadIdx.x;
    if (s < 4096) {
        int lane = s & 63, ks = (s >> 6) & 3, ntile = s >> 8;
        int n = ntile * 16 + (lane & 15);
        int kb = ks * 32 + (lane >> 4) * 8;
#pragma unroll
        for (int j = 0; j < 8; ++j) {
            float w = W1[(kb + j) * L1_OUT + n];
            unsigned short h = bfh(w);
            W1fh[s * 8 + j] = h;
            W1fl[s * 8 + j] = bfh(w - fb(h));
        }
    } else if (s < 6144) {
        int s2 = s - 4096;
        int lane = s2 & 63, ks = (s2 >> 6) & 7, ntile = s2 >> 9;
        int n = ntile * 16 + (lane & 15);
        int kb = ks * 32 + (lane >> 4) * 8;
#pragma unroll
        for (int j = 0; j < 8; ++j) {
            float w = W2[(kb + j) * OUT_DIM + n];
            unsigned short h = bfh(w);
            W2fh[s2 * 8 + j] = h;
            W2fl[s2 * 8 + j] = bfh(w - fb(h));
        }
    }
}

__global__ void scanA_kernel(const int* __restrict__ cnt, int* __restrict__ texcl,
                             int* __restrict__ bsum) {
    __shared__ int sh[SCAN_B];
    int tid = threadIdx.x;
    int i = blockIdx.x * SCAN_B + tid;
    int v = (i < N_NODES) ? cnt[i] : 0;
    sh[tid] = v;
    __syncthreads();
    for (int off = 1; off < SCAN_B; off <<= 1) {
        int t = (tid >= off) ? sh[tid - off] : 0;
        __syncthreads();
        sh[tid] += t;
        __syncthreads();
    }
    if (i < N_NODES) texcl[i] = sh[tid] - v;
    if (tid == SCAN_B - 1) bsum[blockIdx.x] = sh[tid];
}

__global__ void scanB_kernel(const int* __restrict__ bsum, int* __restrict__ bexcl, int nb) {
    __shared__ int sh[SCAN_B];
    int tid = threadIdx.x;
    int v = (tid < nb) ? bsum[tid] : 0;
    sh[tid] = v;
    __syncthreads();
    for (int off = 1; off < SCAN_B; off <<= 1) {
        int t = (tid >= off) ? sh[tid - off] : 0;
        __syncthreads();
        sh[tid] += t;
        __syncthreads();
    }
    if (tid < nb) bexcl[tid] = sh[tid] - v;
}

__global__ void scanC_kernel(const int* __restrict__ texcl, const int* __restrict__ bexcl,
                             int* __restrict__ row) {
    int i = blockIdx.x * blockDim.x + threadIdx.x;
    if (i < N_NODES) row[i] = texcl[i] + bexcl[i >> 8];
    if (blockIdx.x == 0 && threadIdx.x == 0) row[N_NODES] = N_EDGES;
}

__global__ void fill_kernel(const int* __restrict__ src, const int* __restrict__ dst,
                            const int* __restrict__ row, int* __restrict__ fc,
                            int* __restrict__ perm_src) {
    int e = blockIdx.x * blockDim.x + threadIdx.x;
    if (e >= N_EDGES) return;
    int d = dst[e];
    int p = row[d] + atomicAdd(&fc[d], 1);
    perm_src[p] = src[e];
}

// ---------------- gemm1 (MFMA): feat1b = bf16(X @ W1) + fused el1/er1 ----------------
__global__ __launch_bounds__(512) void gemm1_kernel(const float* __restrict__ X,
                                                    const unsigned short* __restrict__ W1fh,
                                                    const unsigned short* __restrict__ W1fl,
                                                    const float* __restrict__ al1,
                                                    const float* __restrict__ ar1,
                                                    unsigned short* __restrict__ feat1b,
                                                    float* __restrict__ el1,
                                                    float* __restrict__ er1) {
    __shared__ unsigned short Ah[4 * 4 * 64 * 8];   // [mfrag][kstep][lane][j]
    __shared__ unsigned short Al[4 * 4 * 64 * 8];
    int t = threadIdx.x;
    int m0 = blockIdx.x * 64;

    // stage X tile (64x128 fp32) -> hi/lo bf16 fragment order
    {
        int m = t >> 3;
        int k0 = (t & 7) * 16;
        int mfrag = m >> 4, mrow = m & 15;
        bool valid = (m0 + m) < N_NODES;
        const float4* xr = (const float4*)&X[(size_t)(m0 + m) * IN_DIM];
#pragma unroll
        for (int g = 0; g < 4; ++g) {
            int k = k0 + g * 4;
            float4 v = valid ? xr[k >> 2] : float4{0.f, 0.f, 0.f, 0.f};
            int kstep = k >> 5, kk = k & 31;
            int lane = mrow + 16 * (kk >> 3);
            int j0 = kk & 7;
            int base = ((mfrag * 4 + kstep) * 64 + lane) * 8 + j0;
            unsigned short h0 = bfh(v.x), h1 = bfh(v.y), h2 = bfh(v.z), h3 = bfh(v.w);
            *(ushort4*)&Ah[base] = make_ushort4(h0, h1, h2, h3);
            *(ushort4*)&Al[base] = make_ushort4(bfh(v.x - fb(h0)), bfh(v.y - fb(h1)),
                                                bfh(v.z - fb(h2)), bfh(v.w - fb(h3)));
        }
    }
    __syncthreads();

    int w = t >> 6, lane = t & 63;
    int wr = w >> 2, wc = w & 3;   // wave tile: rows wr*32..+31, cols wc*64..+63 (head wc)
    f32x4 acc[2][4];
#pragma unroll
    for (int mi = 0; mi < 2; ++mi)
#pragma unroll
        for (int nf = 0; nf < 4; ++nf) acc[mi][nf] = f32x4{0.f, 0.f, 0.f, 0.f};

#pragma unroll
    for (int kstep = 0; kstep < 4; ++kstep) {
        bf16x8 a_h[2], a_l[2];
#pragma unroll
        for (int mi = 0; mi < 2; ++mi) {
            int slot = (((wr * 2 + mi) * 4 + kstep) * 64 + lane) * 8;
            a_h[mi] = *(const bf16x8*)&Ah[slot];
            a_l[mi] = *(const bf16x8*)&Al[slot];
        }
#pragma unroll
        for (int nf = 0; nf < 4; ++nf) {
            int slot = (((wc * 4 + nf) * 4 + kstep) * 64 + lane) * 8;
            bf16x8 b_h = *(const bf16x8*)&W1fh[slot];
            bf16x8 b_l = *(const bf16x8*)&W1fl[slot];
#pragma unroll
            for (int mi = 0; mi < 2; ++mi) {
                acc[mi][nf] = __builtin_amdgcn_mfma_f32_16x16x32_bf16(a_h[mi], b_h, acc[mi][nf], 0, 0, 0);
                acc[mi][nf] = __builtin_amdgcn_mfma_f32_16x16x32_bf16(a_h[mi], b_l, acc[mi][nf], 0, 0, 0);
                acc[mi][nf] = __builtin_amdgcn_mfma_f32_16x16x32_bf16(a_l[mi], b_h, acc[mi][nf], 0, 0, 0);
            }
        }
    }

    // epilogue: D[row=(l>>4)*4+j][col=l&15]
    int fq = lane >> 4, fr = lane & 15;
#pragma unroll
    for (int mi = 0; mi < 2; ++mi) {
#pragma unroll
        for (int j = 0; j < 4; ++j) {
            int r = m0 + wr * 32 + mi * 16 + fq * 4 + j;
            if (r >= N_NODES) continue;
#pragma unroll
            for (int nf = 0; nf < 4; ++nf) {
                int c = wc * 64 + nf * 16 + fr;
                feat1b[(size_t)r * L1_OUT + c] = bfh(acc[mi][nf][j]);
            }
        }
    }

    // fused el/er: wave (wr,wc) head wc rows wr*32..+31; reduce over fr lanes
    float al_v[4], ar_v[4];
#pragma unroll
    for (int nf = 0; nf < 4; ++nf) {
        al_v[nf] = al1[wc * 64 + nf * 16 + fr];
        ar_v[nf] = ar1[wc * 64 + nf * 16 + fr];
    }
#pragma unroll
    for (int mi = 0; mi < 2; ++mi) {
#pragma unroll
        for (int j = 0; j < 4; ++j) {
            float l = 0.f, r = 0.f;
#pragma unroll
            for (int nf = 0; nf < 4; ++nf) {
                l += acc[mi][nf][j] * al_v[nf];
                r += acc[mi][nf][j] * ar_v[nf];
            }
#pragma unroll
            for (int off = 1; off < 16; off <<= 1) {
                l += __shfl_xor(l, off, 64);
                r += __shfl_xor(r, off, 64);
            }
            int rr = m0 + wr * 32 + mi * 16 + fq * 4 + j;
            if (fr == 0 && rr < N_NODES) {
                el1[rr * HEADS + wc] = l;
                er1[rr * HEADS + wc] = r;
            }
        }
    }
}

// ---------------- gather1: fused softmax + aggregate, 4 dsts/block (wave per dst) ----------------
__global__ __launch_bounds__(256) void gather1_kernel(const int* __restrict__ row,
                                                      const int* __restrict__ perm_src,
                                                      const float* __restrict__ el1,
                                                      const float* __restrict__ er1,
                                                      const unsigned short* __restrict__ feat1b,
                                                      float* __restrict__ rst1) {
    __shared__ int psrc[4 * DCHUNK];
    __shared__ float alds[4 * DCHUNK * 4];   // [w][j][h]
    int tid = threadIdx.x;
    int w = tid >> 6, lane = tid & 63;
    int d = blockIdx.x * 4 + w;              // grid is exactly N/4
    int base = row[d], deg = row[d + 1] - base;
    bool fast = (deg > 0) && (deg <= DCHUNK);

    if (fast) {
        // stage edge list (per-wave region)
        for (int j = lane; j < deg; j += 64) psrc[w * DCHUNK + j] = perm_src[base + j];
        int h = lane >> 4, jj = lane & 15;
        float er_d = er1[d * HEADS + h];
        // pass 1: scores -> LDS, track max
        float m = -1e30f;
        for (int j0 = 0; j0 < deg; j0 += 16) {
            int j = j0 + jj;
            if (j < deg) {
                float s = leaky(el1[psrc[w * DCHUNK + j] * HEADS + h] + er_d);
                alds[(w * DCHUNK + j) * 4 + h] = s;
                m = fmaxf(m, s);
            }
        }
#pragma unroll
        for (int off = 1; off < 16; off <<= 1) m = fmaxf(m, __shfl_xor(m, off, 64));
        // pass 2: exp + sum
        float ss = 0.f;
        for (int j0 = 0; j0 < deg; j0 += 16) {
            int j = j0 + jj;
            if (j < deg) {
                float e = __expf(alds[(w * DCHUNK + j) * 4 + h] - m);
                alds[(w * DCHUNK + j) * 4 + h] = e;
                ss += e;
            }
        }
#pragma unroll
        for (int off = 1; off < 16; off <<= 1) ss += __shfl_xor(ss, off, 64);
        float inv = 1.f / ss;
        // pass 3: normalize
        for (int j0 = 0; j0 < deg; j0 += 16) {
            int j = j0 + jj;
            if (j < deg) alds[(w * DCHUNK + j) * 4 + h] *= inv;
        }
    }
    __syncthreads();

    float4* out4 = (float4*)&rst1[(size_t)d * L1_OUT];
    if (deg == 0) {
        out4[lane] = float4{0.f, 0.f, 0.f, 0.f};
    } else if (fast) {
        int hh = lane >> 4;   // head of channels lane*4..lane*4+3
        const ushort4* f4 = (const ushort4*)feat1b;
        float4 a0 = {0.f, 0.f, 0.f, 0.f}, a1 = {0.f, 0.f, 0.f, 0.f};
        float4 a2 = {0.f, 0.f, 0.f, 0.f}, a3 = {0.f, 0.f, 0.f, 0.f};
        int j = 0;
        for (; j + 3 < deg; j += 4) {
            int s0 = psrc[w * DCHUNK + j], s1 = psrc[w * DCHUNK + j + 1];
            int s2 = psrc[w * DCHUNK + j + 2], s3 = psrc[w * DCHUNK + j + 3];
            float w0 = alds[(w * DCHUNK + j) * 4 + hh], w1 = alds[(w * DCHUNK + j + 1) * 4 + hh];
            float w2 = alds[(w * DCHUNK + j + 2) * 4 + hh], w3 = alds[(w * DCHUNK + j + 3) * 4 + hh];
            ushort4 f0 = f4[(size_t)s0 * 64 + lane];
            ushort4 f1 = f4[(size_t)s1 * 64 + lane];
            ushort4 f2 = f4[(size_t)s2 * 64 + lane];
            ushort4 f3 = f4[(size_t)s3 * 64 + lane];
            a0.x += w0 * fb(f0.x); a0.y += w0 * fb(f0.y); a0.z += w0 * fb(f0.z); a0.w += w0 * fb(f0.w);
            a1.x += w1 * fb(f1.x); a1.y += w1 * fb(f1.y); a1.z += w1 * fb(f1.z); a1.w += w1 * fb(f1.w);
            a2.x += w2 * fb(f2.x); a2.y += w2 * fb(f2.y); a2.z += w2 * fb(f2.z); a2.w += w2 * fb(f2.w);
            a3.x += w3 * fb(f3.x); a3.y += w3 * fb(f3.y); a3.z += w3 * fb(f3.z); a3.w += w3 * fb(f3.w);
        }
        for (; j < deg; ++j) {
            int s0 = psrc[w * DCHUNK + j];
            float w0 = alds[(w * DCHUNK + j) * 4 + hh];
            ushort4 f0 = f4[(size_t)s0 * 64 + lane];
            a0.x += w0 * fb(f0.x); a0.y += w0 * fb(f0.y); a0.z += w0 * fb(f0.z); a0.w += w0 * fb(f0.w);
        }
        float4 r;
        r.x = a0.x + a1.x + a2.x + a3.x;
        r.y = a0.y + a1.y + a2.y + a3.y;
        r.z = a0.z + a1.z + a2.z + a3.z;
        r.w = a0.w + a1.w + a2.w + a3.w;
        out4[lane] = r;
    } else {
        // fallback deg > DCHUNK: wave handles all heads, no barriers
        float mh0, mh1, mh2, mh3, iv0, iv1, iv2, iv3;
#pragma unroll
        for (int h = 0; h < 4; ++h) {
            float er_dh = er1[d * HEADS + h];
            float m = -1e30f;
            for (int j = lane; j < deg; j += 64)
                m = fmaxf(m, leaky(el1[perm_src[base + j] * HEADS + h] + er_dh));
#pragma unroll
            for (int off = 1; off < 64; off <<= 1) m = fmaxf(m, __shfl_xor(m, off, 64));
            float ss = 0.f;
            for (int j = lane; j < deg; j += 64)
                ss += __expf(leaky(el1[perm_src[base + j] * HEADS + h] + er_dh) - m);
#pragma unroll
            for (int off = 1; off < 64; off <<= 1) ss += __shfl_xor(ss, off, 64);
            float iv = 1.f / ss;
            if (h == 0) { mh0 = m; iv0 = iv; }
            else if (h == 1) { mh1 = m; iv1 = iv; }
            else if (h == 2) { mh2 = m; iv2 = iv; }
            else { mh3 = m; iv3 = iv; }
        }
        int hh = lane >> 4;
        float m_s = hh == 0 ? mh0 : hh == 1 ? mh1 : hh == 2 ? mh2 : mh3;
        float iv_s = hh == 0 ? iv0 : hh == 1 ? iv1 : hh == 2 ? iv2 : iv3;
        float er_s = er1[d * HEADS + hh];
        const ushort4* f4 = (const ushort4*)feat1b;
        float4 a0 = {0.f, 0.f, 0.f, 0.f};
        for (int j = 0; j < deg; ++j) {
            int s = perm_src[base + j];
            float a = __expf(leaky(el1[s * HEADS + hh] + er_s) - m_s) * iv_s;
            ushort4 f0 = f4[(size_t)s * 64 + lane];
            a0.x += a * fb(f0.x); a0.y += a * fb(f0.y); a0.z += a * fb(f0.z); a0.w += a * fb(f0.w);
        }
        out4[lane] = a0;
    }
}

// ---------------- gemm2 (MFMA): feat2b = bf16((rst1+b1) @ W2) + fused el2/er2 ----------------
__global__ __launch_bounds__(256) void gemm2_kernel(const float* __restrict__ rst1,
                                                    const float* __restrict__ b1,
                                                    const unsigned short* __restrict__ W2fh,
                                                    const unsigned short* __restrict__ W2fl,
                                                    const float* __restrict__ al2,
                                                    const float* __restrict__ ar2,
                                                    unsigned short* __restrict__ feat2b,
                                                    float* __restrict__ el2,
                                                    float* __restrict__ er2) {
    __shared__ unsigned short Ah[2 * 8 * 64 * 8];   // [mfrag][kstep][lane][j]
    __shared__ unsigned short Al[2 * 8 * 64 * 8];
    __shared__ float pl[2][2][16], pr[2][2][16];    // [nh][mi][row]
    int t = threadIdx.x;
    int n0 = blockIdx.x * 32;

    {
        int m = t >> 3;
        int kstep = t & 7;
        int mfrag = m >> 4, mrow = m & 15;
        bool valid = (n0 + m) < N_NODES;
        const float4* ar4 = (const float4*)&rst1[(size_t)(n0 + m) * L1_OUT];
        const float4* br4 = (const float4*)b1;
#pragma unroll
        for (int g = 0; g < 8; ++g) {
            int k = kstep * 32 + g * 4;
            float4 v = valid ? ar4[k >> 2] : float4{0.f, 0.f, 0.f, 0.f};
            float4 bb = br4[k >> 2];
            v.x += bb.x; v.y += bb.y; v.z += bb.z; v.w += bb.w;
            if (!valid) { v.x = 0.f; v.y = 0.f; v.z = 0.f; v.w = 0.f; }
            int lane = mrow + 16 * (g >> 1);
            int j0 = (g & 1) * 4;
            int base = ((mfrag * 8 + kstep) * 64 + lane) * 8 + j0;
            unsigned short h0 = bfh(v.x), h1 = bfh(v.y), h2 = bfh(v.z), h3 = bfh(v.w);
            *(ushort4*)&Ah[base] = make_ushort4(h0, h1, h2, h3);
            *(ushort4*)&Al[base] = make_ushort4(bfh(v.x - fb(h0)), bfh(v.y - fb(h1)),
                                                bfh(v.z - fb(h2)), bfh(v.w - fb(h3)));
        }
    }
    __syncthreads();

    int w = t >> 6, lane = t & 63;
    int mi = w >> 1, nh = w & 1;    // wave: rows mi*16..+15, n-frags nh*2..nh*2+1
    f32x4 acc[2];
    acc[0] = f32x4{0.f, 0.f, 0.f, 0.f};
    acc[1] = f32x4{0.f, 0.f, 0.f, 0.f};

#pragma unroll
    for (int ks = 0; ks < 8; ++ks) {
        int aslot = ((mi * 8 + ks) * 64 + lane) * 8;
        bf16x8 a_h = *(const bf16x8*)&Ah[aslot];
        bf16x8 a_l = *(const bf16x8*)&Al[aslot];
#pragma unroll
        for (int nf = 0; nf < 2; ++nf) {
            int ntile = nh * 2 + nf;
            int slot = ((ntile * 8 + ks) * 64 + lane) * 8;
            bf16x8 b_h = *(const bf16x8*)&W2fh[slot];
            bf16x8 b_l = *(const bf16x8*)&W2fl[slot];
            acc[nf] = __builtin_amdgcn_mfma_f32_16x16x32_bf16(a_h, b_h, acc[nf], 0, 0, 0);
            acc[nf] = __builtin_amdgcn_mfma_f32_16x16x32_bf16(a_h, b_l, acc[nf], 0, 0, 0);
            acc[nf] = __builtin_amdgcn_mfma_f32_16x16x32_bf16(a_l, b_h, acc[nf], 0, 0, 0);
        }
    }

    int fq = lane >> 4, fr = lane & 15;
#pragma unroll
    for (int j = 0; j < 4; ++j) {
        int r = n0 + mi * 16 + fq * 4 + j;
        if (r >= N_NODES) continue;
#pragma unroll
        for (int nf = 0; nf < 2; ++nf) {
            int c = (nh * 2 + nf) * 16 + fr;
            feat2b[(size_t)r * OUT_DIM + c] = bfh(acc[nf][j]);
        }
    }

    // fused el2/er2: partial over this wave's 32 cols, combine across nh in LDS
    float al_v[2], ar_v[2];
#pragma unroll
    for (int nf = 0; nf < 2; ++nf) {
        al_v[nf] = al2[(nh * 2 + nf) * 16 + fr];
        ar_v[nf] = ar2[(nh * 2 + nf) * 16 + fr];
    }
#pragma unroll
    for (int j = 0; j < 4; ++j) {
        float l = acc[0][j] * al_v[0] + acc[1][j] * al_v[1];
        float r = acc[0][j] * ar_v[0] + acc[1][j] * ar_v[1];
#pragma unroll
        for (int off = 1; off < 16; off <<= 1) {
            l += __shfl_xor(l, off, 64);
            r += __shfl_xor(r, off, 64);
        }
        if (fr == 0) {
            pl[nh][mi][fq * 4 + j] = l;
            pr[nh][mi][fq * 4 + j] = r;
        }
    }
    __syncthreads();
    if (t < 32) {
        int n = n0 + t;
        if (n < N_NODES) {
            int mi2 = t >> 4, rr = t & 15;
            el2[n] = pl[0][mi2][rr] + pl[1][mi2][rr];
            er2[n] = pr[0][mi2][rr] + pr[1][mi2][rr];
        }
    }
}

// ---------------- gather2: fused softmax + aggregate + bias, 4 dsts/block ----------------
__global__ __launch_bounds__(256) void gather2_kernel(const int* __restrict__ row,
                                                      const int* __restrict__ perm_src,
                                                      const float* __restrict__ el2,
                                                      const float* __restrict__ er2,
                                                      const unsigned short* __restrict__ feat2b,
                                                      const float* __restrict__ b2,
                                                      float* __restrict__ out) {
    __shared__ int psrc[4 * DCHUNK];
    __shared__ float alds[4 * DCHUNK];
    int tid = threadIdx.x;
    int w = tid >> 6, lane = tid & 63;
    int d = blockIdx.x * 4 + w;
    int base = row[d], deg = row[d + 1] - base;
    bool fast = (deg > 0) && (deg <= DCHUNK);

    if (fast) {
        for (int j = lane; j < deg; j += 64) psrc[w * DCHUNK + j] = perm_src[base + j];
        float er_d = er2[d];
        float m = -1e30f;
        for (int j0 = 0; j0 < deg; j0 += 64) {
            int j = j0 + lane;
            if (j < deg) {
                float s = leaky(el2[psrc[w * DCHUNK + j]] + er_d);
                alds[w * DCHUNK + j] = s;
                m = fmaxf(m, s);
            }
        }
#pragma unroll
        for (int off = 1; off < 64; off <<= 1) m = fmaxf(m, __shfl_xor(m, off, 64));
        float ss = 0.f;
        for (int j0 = 0; j0 < deg; j0 += 64) {
            int j = j0 + lane;
            if (j < deg) {
                float e = __expf(alds[w * DCHUNK + j] - m);
                alds[w * DCHUNK + j] = e;
                ss += e;
            }
        }
#pragma unroll
        for (int off = 1; off < 64; off <<= 1) ss += __shfl_xor(ss, off, 64);
        float inv = 1.f / ss;
        for (int j0 = 0; j0 < deg; j0 += 64) {
            int j = j0 + lane;
            if (j < deg) alds[w * DCHUNK + j] *= inv;
        }
    }
    __syncthreads();

    if (deg == 0) {
        out[(size_t)d * OUT_DIM + lane] = b2[lane];
    } else if (fast) {
        float a0 = 0.f, a1 = 0.f, a2 = 0.f, a3 = 0.f;
        int j = 0;
        for (; j + 3 < deg; j += 4) {
            int s0 = psrc[w * DCHUNK + j], s1 = psrc[w * DCHUNK + j + 1];
            int s2 = psrc[w * DCHUNK + j + 2], s3 = psrc[w * DCHUNK + j + 3];
            float w0 = alds[w * DCHUNK + j], w1 = alds[w * DCHUNK + j + 1];
            float w2 = alds[w * DCHUNK + j + 2], w3 = alds[w * DCHUNK + j + 3];
            a0 += w0 * fb(feat2b[(size_t)s0 * OUT_DIM + lane]);
            a1 += w1 * fb(feat2b[(size_t)s1 * OUT_DIM + lane]);
            a2 += w2 * fb(feat2b[(size_t)s2 * OUT_DIM + lane]);
            a3 += w3 * fb(feat2b[(size_t)s3 * OUT_DIM + lane]);
        }
        for (; j < deg; ++j) {
            a0 += alds[w * DCHUNK + j] * fb(feat2b[(size_t)psrc[w * DCHUNK + j] * OUT_DIM + lane]);
        }
        out[(size_t)d * OUT_DIM + lane] = a0 + a1 + a2 + a3 + b2[lane];
    } else {
        // fallback deg > DCHUNK
        float er_d = er2[d];
        float m = -1e30f;
        for (int j = lane; j < deg; j += 64)
            m = fmaxf(m, leaky(el2[perm_src[base + j]] + er_d));
#pragma unroll
        for (int off = 1; off < 64; off <<= 1) m = fmaxf(m, __shfl_xor(m, off, 64));
        float ss = 0.f;
        for (int j = lane; j < deg; j += 64)
            ss += __expf(leaky(el2[perm_src[base + j]] + er_d) - m);
#pragma unroll
        for (int off = 1; off < 64; off <<= 1) ss += __shfl_xor(ss, off, 64);
        float inv = 1.f / ss;
        float a0 = 0.f;
        for (int j = 0; j < deg; ++j) {
            int s = perm_src[base + j];
            float a = __expf(leaky(el2[s] + er_d) - m) * inv;
            a0 += a * fb(feat2b[(size_t)s * OUT_DIM + lane]);
        }
        out[(size_t)d * OUT_DIM + lane] = a0 + b2[lane];
    }
}

extern "C" void kernel_launch(void* const* d_in, const int* in_sizes, int n_in,
                              void* d_out, int out_size, void* d_ws, size_t ws_size,
                              hipStream_t stream) {
    const float* features = (const float*)d_in[0];
    const int* src = (const int*)d_in[1];
    const int* dst = (const int*)d_in[2];
    const float* W1 = (const float*)d_in[3];
    const float* al1 = (const float*)d_in[4];
    const float* ar1 = (const float*)d_in[5];
    const float* b1 = (const float*)d_in[6];
    const float* W2 = (const float*)d_in[7];
    const float* al2 = (const float*)d_in[8];
    const float* ar2 = (const float*)d_in[9];
    const float* b2 = (const float*)d_in[10];
    float* out = (float*)d_out;

    // workspace layout
    float* ws = (float*)d_ws;
    float* rst1 = ws;                                          // N*256 f32
    float* el1 = rst1 + (size_t)N_NODES * L1_OUT;              // N*4
    float* er1 = el1 + N_NODES * HEADS;                        // N*4
    float* el2 = er1 + N_NODES * HEADS;                        // N
    float* er2 = el2 + N_NODES;                                // N
    unsigned short* feat1b = (unsigned short*)(er2 + N_NODES); // N*256 bf16
    unsigned short* feat2b = feat1b + (size_t)N_NODES * L1_OUT;// N*64 bf16
    unsigned short* W1fh = feat2b + (size_t)N_NODES * OUT_DIM; // 32768
    unsigned short* W1fl = W1fh + 32768;                       // 32768
    unsigned short* W2fh = W1fl + 32768;                       // 16384
    unsigned short* W2fl = W2fh + 16384;                       // 16384
    int* cnt = (int*)(W2fl + 16384);                           // N
    int* fc = cnt + N_NODES;                                   // N
    int* texcl = fc + N_NODES;                                 // N
    int* bsum = texcl + N_NODES;                               // 256
    int* bexcl = bsum + 256;                                   // 256
    int* row = bexcl + 256;                                    // N+1
    int* perm_src = row + N_NODES + 1;                         // E

    const int nscan = (N_NODES + SCAN_B - 1) / SCAN_B;   // 196

    hipMemsetAsync(cnt, 0, (size_t)2 * N_NODES * sizeof(int), stream);  // cnt + fc

    // CSR build + weight prep
    hist_wprep_kernel<<<HIST_B + 24, 256, 0, stream>>>(dst, cnt, W1, W2, W1fh, W1fl, W2fh, W2fl);
    scanA_kernel<<<nscan, SCAN_B, 0, stream>>>(cnt, texcl, bsum);
    scanB_kernel<<<1, SCAN_B, 0, stream>>>(bsum, bexcl, nscan);
    scanC_kernel<<<(N_NODES + 255) / 256, 256, 0, stream>>>(texcl, bexcl, row);
    fill_kernel<<<(N_EDGES + 255) / 256, 256, 0, stream>>>(src, dst, row, fc, perm_src);

    // layer 1
    gemm1_kernel<<<(N_NODES + 63) / 64, 512, 0, stream>>>(features, W1fh, W1fl, al1, ar1,
                                                          feat1b, el1, er1);
    gather1_kernel<<<N_NODES / 4, 256, 0, stream>>>(row, perm_src, el1, er1, feat1b, rst1);

    // layer 2
    gemm2_kernel<<<(N_NODES + 31) / 32, 256, 0, stream>>>(rst1, b1, W2fh, W2fl, al2, ar2,
                                                          feat2b, el2, er2);
    gather2_kernel<<<N_NODES / 4, 256, 0, stream>>>(row, perm_src, el2, er2, feat2b, b2, out);
}

// Round 6
// 181.694 us; speedup vs baseline: 2.0383x; 1.0671x over previous
//
#include <hip/hip_runtime.h>
#include <hip/hip_bf16.h>

#define N_NODES 50000
#define N_EDGES 400000
#define IN_DIM 128
#define HID 64
#define HEADS 4
#define L1_OUT (HEADS * HID)   // 256
#define OUT_DIM 64
#define NEG_SLOPE 0.2f
#define SCAN_B 256
#define HIST_B 1563            // ceil(400000/256)

typedef short bf16x8 __attribute__((ext_vector_type(8)));
typedef float f32x4 __attribute__((ext_vector_type(4)));

__device__ __forceinline__ float leaky(float x) { return x > 0.f ? x : NEG_SLOPE * x; }

// RNE float->bf16 bits, bf16 bits->float
__device__ __forceinline__ unsigned short bfh(float x) {
    unsigned u = __float_as_uint(x);
    return (unsigned short)((u + 0x7fffu + ((u >> 16) & 1u)) >> 16);
}
__device__ __forceinline__ float fb(unsigned short h) {
    return __uint_as_float(((unsigned)h) << 16);
}

// ---------------- CSR hist + W fragment prep (merged) ----------------
__global__ void hist_wprep_kernel(const int* __restrict__ dst, int* __restrict__ cnt,
                                  const float* __restrict__ W1, const float* __restrict__ W2,
                                  unsigned short* __restrict__ W1fh, unsigned short* __restrict__ W1fl,
                                  unsigned short* __restrict__ W2fh, unsigned short* __restrict__ W2fl) {
    int bid = blockIdx.x;
    if (bid < HIST_B) {
        int e = bid * 256 + threadIdx.x;
        if (e < N_EDGES) atomicAdd(&cnt[dst[e]], 1);
        return;
    }
    int s = (bid - HIST_B) * 256 + threadIdx.x;
    if (s < 4096) {
        int lane = s & 63, ks = (s >> 6) & 3, ntile = s >> 8;
        int n = ntile * 16 + (lane & 15);
        int kb = ks * 32 + (lane >> 4) * 8;
#pragma unroll
        for (int j = 0; j < 8; ++j) {
            float w = W1[(kb + j) * L1_OUT + n];
            unsigned short h = bfh(w);
            W1fh[s * 8 + j] = h;
            W1fl[s * 8 + j] = bfh(w - fb(h));
        }
    } else if (s < 6144) {
        int s2 = s - 4096;
        int lane = s2 & 63, ks = (s2 >> 6) & 7, ntile = s2 >> 9;
        int n = ntile * 16 + (lane & 15);
        int kb = ks * 32 + (lane >> 4) * 8;
#pragma unroll
        for (int j = 0; j < 8; ++j) {
            float w = W2[(kb + j) * OUT_DIM + n];
            unsigned short h = bfh(w);
            W2fh[s2 * 8 + j] = h;
            W2fl[s2 * 8 + j] = bfh(w - fb(h));
        }
    }
}

__global__ void scanA_kernel(const int* __restrict__ cnt, int* __restrict__ texcl,
                             int* __restrict__ bsum) {
    __shared__ int sh[SCAN_B];
    int tid = threadIdx.x;
    int i = blockIdx.x * SCAN_B + tid;
    int v = (i < N_NODES) ? cnt[i] : 0;
    sh[tid] = v;
    __syncthreads();
    for (int off = 1; off < SCAN_B; off <<= 1) {
        int t = (tid >= off) ? sh[tid - off] : 0;
        __syncthreads();
        sh[tid] += t;
        __syncthreads();
    }
    if (i < N_NODES) texcl[i] = sh[tid] - v;
    if (tid == SCAN_B - 1) bsum[blockIdx.x] = sh[tid];
}

__global__ void scanB_kernel(const int* __restrict__ bsum, int* __restrict__ bexcl, int nb) {
    __shared__ int sh[SCAN_B];
    int tid = threadIdx.x;
    int v = (tid < nb) ? bsum[tid] : 0;
    sh[tid] = v;
    __syncthreads();
    for (int off = 1; off < SCAN_B; off <<= 1) {
        int t = (tid >= off) ? sh[tid - off] : 0;
        __syncthreads();
        sh[tid] += t;
        __syncthreads();
    }
    if (tid < nb) bexcl[tid] = sh[tid] - v;
}

__global__ void scanC_kernel(const int* __restrict__ texcl, const int* __restrict__ bexcl,
                             int* __restrict__ row) {
    int i = blockIdx.x * blockDim.x + threadIdx.x;
    if (i < N_NODES) row[i] = texcl[i] + bexcl[i >> 8];
    if (blockIdx.x == 0 && threadIdx.x == 0) row[N_NODES] = N_EDGES;
}

__global__ void fill_kernel(const int* __restrict__ src, const int* __restrict__ dst,
                            const int* __restrict__ row, int* __restrict__ fc,
                            int* __restrict__ perm_src) {
    int e = blockIdx.x * blockDim.x + threadIdx.x;
    if (e >= N_EDGES) return;
    int d = dst[e];
    int p = row[d] + atomicAdd(&fc[d], 1);
    perm_src[p] = src[e];
}

// ---------------- gemm1 (MFMA): feat1b = bf16(X @ W1) + fused el1/er1 ----------------
__global__ __launch_bounds__(512) void gemm1_kernel(const float* __restrict__ X,
                                                    const unsigned short* __restrict__ W1fh,
                                                    const unsigned short* __restrict__ W1fl,
                                                    const float* __restrict__ al1,
                                                    const float* __restrict__ ar1,
                                                    unsigned short* __restrict__ feat1b,
                                                    float* __restrict__ el1,
                                                    float* __restrict__ er1) {
    __shared__ unsigned short Ah[4 * 4 * 64 * 8];   // [mfrag][kstep][lane][j]
    __shared__ unsigned short Al[4 * 4 * 64 * 8];
    int t = threadIdx.x;
    int m0 = blockIdx.x * 64;

    {
        int m = t >> 3;
        int k0 = (t & 7) * 16;
        int mfrag = m >> 4, mrow = m & 15;
        bool valid = (m0 + m) < N_NODES;
        const float4* xr = (const float4*)&X[(size_t)(m0 + m) * IN_DIM];
#pragma unroll
        for (int g = 0; g < 4; ++g) {
            int k = k0 + g * 4;
            float4 v = valid ? xr[k >> 2] : float4{0.f, 0.f, 0.f, 0.f};
            int kstep = k >> 5, kk = k & 31;
            int lane = mrow + 16 * (kk >> 3);
            int j0 = kk & 7;
            int base = ((mfrag * 4 + kstep) * 64 + lane) * 8 + j0;
            unsigned short h0 = bfh(v.x), h1 = bfh(v.y), h2 = bfh(v.z), h3 = bfh(v.w);
            *(ushort4*)&Ah[base] = make_ushort4(h0, h1, h2, h3);
            *(ushort4*)&Al[base] = make_ushort4(bfh(v.x - fb(h0)), bfh(v.y - fb(h1)),
                                                bfh(v.z - fb(h2)), bfh(v.w - fb(h3)));
        }
    }
    __syncthreads();

    int w = t >> 6, lane = t & 63;
    int wr = w >> 2, wc = w & 3;   // wave tile: rows wr*32..+31, cols wc*64..+63 (head wc)
    f32x4 acc[2][4];
#pragma unroll
    for (int mi = 0; mi < 2; ++mi)
#pragma unroll
        for (int nf = 0; nf < 4; ++nf) acc[mi][nf] = f32x4{0.f, 0.f, 0.f, 0.f};

#pragma unroll
    for (int kstep = 0; kstep < 4; ++kstep) {
        bf16x8 a_h[2], a_l[2];
#pragma unroll
        for (int mi = 0; mi < 2; ++mi) {
            int slot = (((wr * 2 + mi) * 4 + kstep) * 64 + lane) * 8;
            a_h[mi] = *(const bf16x8*)&Ah[slot];
            a_l[mi] = *(const bf16x8*)&Al[slot];
        }
#pragma unroll
        for (int nf = 0; nf < 4; ++nf) {
            int slot = (((wc * 4 + nf) * 4 + kstep) * 64 + lane) * 8;
            bf16x8 b_h = *(const bf16x8*)&W1fh[slot];
            bf16x8 b_l = *(const bf16x8*)&W1fl[slot];
#pragma unroll
            for (int mi = 0; mi < 2; ++mi) {
                acc[mi][nf] = __builtin_amdgcn_mfma_f32_16x16x32_bf16(a_h[mi], b_h, acc[mi][nf], 0, 0, 0);
                acc[mi][nf] = __builtin_amdgcn_mfma_f32_16x16x32_bf16(a_h[mi], b_l, acc[mi][nf], 0, 0, 0);
                acc[mi][nf] = __builtin_amdgcn_mfma_f32_16x16x32_bf16(a_l[mi], b_h, acc[mi][nf], 0, 0, 0);
            }
        }
    }

    int fq = lane >> 4, fr = lane & 15;
#pragma unroll
    for (int mi = 0; mi < 2; ++mi) {
#pragma unroll
        for (int j = 0; j < 4; ++j) {
            int r = m0 + wr * 32 + mi * 16 + fq * 4 + j;
            if (r >= N_NODES) continue;
#pragma unroll
            for (int nf = 0; nf < 4; ++nf) {
                int c = wc * 64 + nf * 16 + fr;
                feat1b[(size_t)r * L1_OUT + c] = bfh(acc[mi][nf][j]);
            }
        }
    }

    float al_v[4], ar_v[4];
#pragma unroll
    for (int nf = 0; nf < 4; ++nf) {
        al_v[nf] = al1[wc * 64 + nf * 16 + fr];
        ar_v[nf] = ar1[wc * 64 + nf * 16 + fr];
    }
#pragma unroll
    for (int mi = 0; mi < 2; ++mi) {
#pragma unroll
        for (int j = 0; j < 4; ++j) {
            float l = 0.f, r = 0.f;
#pragma unroll
            for (int nf = 0; nf < 4; ++nf) {
                l += acc[mi][nf][j] * al_v[nf];
                r += acc[mi][nf][j] * ar_v[nf];
            }
#pragma unroll
            for (int off = 1; off < 16; off <<= 1) {
                l += __shfl_xor(l, off, 64);
                r += __shfl_xor(r, off, 64);
            }
            int rr = m0 + wr * 32 + mi * 16 + fq * 4 + j;
            if (fr == 0 && rr < N_NODES) {
                el1[rr * HEADS + wc] = l;
                er1[rr * HEADS + wc] = r;
            }
        }
    }
}

// ---------------- layer2 fused: gather1 (into LDS A-frags) + gemm2 MFMA + el2/er2 ----------------
// Block = 256 threads = 4 waves, owns 32 consecutive dsts (8 iterations x 4 waves).
__global__ __launch_bounds__(256) void layer2_kernel(const int* __restrict__ row,
                                                     const int* __restrict__ perm_src,
                                                     const float* __restrict__ el1,
                                                     const float* __restrict__ er1,
                                                     const unsigned short* __restrict__ feat1b,
                                                     const float* __restrict__ b1,
                                                     const unsigned short* __restrict__ W2fh,
                                                     const unsigned short* __restrict__ W2fl,
                                                     const float* __restrict__ al2,
                                                     const float* __restrict__ ar2,
                                                     unsigned short* __restrict__ feat2b,
                                                     float* __restrict__ el2,
                                                     float* __restrict__ er2) {
    __shared__ unsigned short Ah[2 * 8 * 64 * 8];   // [mfrag][kstep][lane][j] 16 KB
    __shared__ unsigned short Al[2 * 8 * 64 * 8];   // 16 KB
    __shared__ float pl[2][2][16], pr[2][2][16];
    int t = threadIdx.x;
    int w = t >> 6, lane = t & 63;
    int n0 = blockIdx.x * 32;

    float4 b1v = *(const float4*)&b1[lane * 4];   // channels lane*4..+3
    const ushort4* f4 = (const ushort4*)feat1b;

    // ---- phase 1: aggregate 32 dst rows into LDS A-fragments (hi/lo bf16) ----
#pragma unroll 1
    for (int it = 0; it < 8; ++it) {
        int d = n0 + it * 4 + w;
        float4 acc = {0.f, 0.f, 0.f, 0.f};
        bool valid = d < N_NODES;
        if (valid) {
            int base = row[d], deg = row[d + 1] - base;
            if (deg > 0 && deg <= 16) {
                // register softmax: 16-lane group per head, lane jj = edge jj
                int h = lane >> 4, jj = lane & 15;
                int s_reg = (jj < deg) ? perm_src[base + jj] : 0;
                float er_d = er1[d * HEADS + h];
                float sc = (jj < deg) ? leaky(el1[s_reg * HEADS + h] + er_d) : -1e30f;
                float m = sc;
                m = fmaxf(m, __shfl_xor(m, 1, 64));
                m = fmaxf(m, __shfl_xor(m, 2, 64));
                m = fmaxf(m, __shfl_xor(m, 4, 64));
                m = fmaxf(m, __shfl_xor(m, 8, 64));
                float ex = (jj < deg) ? __expf(sc - m) : 0.f;
                float ss = ex;
                ss += __shfl_xor(ss, 1, 64);
                ss += __shfl_xor(ss, 2, 64);
                ss += __shfl_xor(ss, 4, 64);
                ss += __shfl_xor(ss, 8, 64);
                float alpha = ex / ss;
                // aggregation: lane = 4 channels of head (lane>>4); alpha via bpermute
                int hb = lane & 48;
                float4 A0 = {0.f,0.f,0.f,0.f}, A1 = {0.f,0.f,0.f,0.f};
                float4 A2 = {0.f,0.f,0.f,0.f}, A3 = {0.f,0.f,0.f,0.f};
                int j = 0;
                for (; j + 3 < deg; j += 4) {
                    int s0 = __shfl(s_reg, j), s1 = __shfl(s_reg, j + 1);
                    int s2 = __shfl(s_reg, j + 2), s3 = __shfl(s_reg, j + 3);
                    float a0 = __shfl(alpha, hb + j), a1 = __shfl(alpha, hb + j + 1);
                    float a2 = __shfl(alpha, hb + j + 2), a3 = __shfl(alpha, hb + j + 3);
                    ushort4 f0 = f4[(size_t)s0 * 64 + lane];
                    ushort4 f1 = f4[(size_t)s1 * 64 + lane];
                    ushort4 f2 = f4[(size_t)s2 * 64 + lane];
                    ushort4 f3 = f4[(size_t)s3 * 64 + lane];
                    A0.x += a0 * fb(f0.x); A0.y += a0 * fb(f0.y); A0.z += a0 * fb(f0.z); A0.w += a0 * fb(f0.w);
                    A1.x += a1 * fb(f1.x); A1.y += a1 * fb(f1.y); A1.z += a1 * fb(f1.z); A1.w += a1 * fb(f1.w);
                    A2.x += a2 * fb(f2.x); A2.y += a2 * fb(f2.y); A2.z += a2 * fb(f2.z); A2.w += a2 * fb(f2.w);
                    A3.x += a3 * fb(f3.x); A3.y += a3 * fb(f3.y); A3.z += a3 * fb(f3.z); A3.w += a3 * fb(f3.w);
                }
                for (; j < deg; ++j) {
                    int s0 = __shfl(s_reg, j);
                    float a0 = __shfl(alpha, hb + j);
                    ushort4 f0 = f4[(size_t)s0 * 64 + lane];
                    A0.x += a0 * fb(f0.x); A0.y += a0 * fb(f0.y); A0.z += a0 * fb(f0.z); A0.w += a0 * fb(f0.w);
                }
                acc.x = A0.x + A1.x + A2.x + A3.x;
                acc.y = A0.y + A1.y + A2.y + A3.y;
                acc.z = A0.z + A1.z + A2.z + A3.z;
                acc.w = A0.w + A1.w + A2.w + A3.w;
            } else if (deg > 16) {
                // rare fallback: strided per-head stats, serial recompute aggregation
                float mh0, mh1, mh2, mh3, iv0, iv1, iv2, iv3;
#pragma unroll
                for (int h = 0; h < 4; ++h) {
                    float er_dh = er1[d * HEADS + h];
                    float m = -1e30f;
                    for (int j = lane; j < deg; j += 64)
                        m = fmaxf(m, leaky(el1[perm_src[base + j] * HEADS + h] + er_dh));
#pragma unroll
                    for (int off = 1; off < 64; off <<= 1) m = fmaxf(m, __shfl_xor(m, off, 64));
                    float ss = 0.f;
                    for (int j = lane; j < deg; j += 64)
                        ss += __expf(leaky(el1[perm_src[base + j] * HEADS + h] + er_dh) - m);
#pragma unroll
                    for (int off = 1; off < 64; off <<= 1) ss += __shfl_xor(ss, off, 64);
                    float iv = 1.f / ss;
                    if (h == 0) { mh0 = m; iv0 = iv; }
                    else if (h == 1) { mh1 = m; iv1 = iv; }
                    else if (h == 2) { mh2 = m; iv2 = iv; }
                    else { mh3 = m; iv3 = iv; }
                }
                int hh = lane >> 4;
                float m_s = hh == 0 ? mh0 : hh == 1 ? mh1 : hh == 2 ? mh2 : mh3;
                float iv_s = hh == 0 ? iv0 : hh == 1 ? iv1 : hh == 2 ? iv2 : iv3;
                float er_s = er1[d * HEADS + hh];
                for (int j = 0; j < deg; ++j) {
                    int s = perm_src[base + j];
                    float a = __expf(leaky(el1[s * HEADS + hh] + er_s) - m_s) * iv_s;
                    ushort4 f0 = f4[(size_t)s * 64 + lane];
                    acc.x += a * fb(f0.x); acc.y += a * fb(f0.y);
                    acc.z += a * fb(f0.z); acc.w += a * fb(f0.w);
                }
            }
            // deg==0: acc stays 0
            acc.x += b1v.x; acc.y += b1v.y; acc.z += b1v.z; acc.w += b1v.w;
        }
        // write row m = it*4+w, channels lane*4..+3 into A-frag layout (hi/lo)
        int m = it * 4 + w;
        int mfrag = m >> 4, mrow = m & 15;
        int c = lane * 4;
        int kstep = c >> 5;
        int fraglane = mrow + 16 * ((c & 31) >> 3);
        int j0 = c & 7;
        int basei = ((mfrag * 8 + kstep) * 64 + fraglane) * 8 + j0;
        unsigned short h0 = bfh(acc.x), h1 = bfh(acc.y), h2 = bfh(acc.z), h3 = bfh(acc.w);
        *(ushort4*)&Ah[basei] = make_ushort4(h0, h1, h2, h3);
        *(ushort4*)&Al[basei] = make_ushort4(bfh(acc.x - fb(h0)), bfh(acc.y - fb(h1)),
                                             bfh(acc.z - fb(h2)), bfh(acc.w - fb(h3)));
    }
    __syncthreads();

    // ---- phase 2: gemm2 MFMA ----
    int mi = w >> 1, nh = w & 1;    // wave: rows mi*16..+15, n-frags nh*2..nh*2+1
    f32x4 acc2[2];
    acc2[0] = f32x4{0.f, 0.f, 0.f, 0.f};
    acc2[1] = f32x4{0.f, 0.f, 0.f, 0.f};

#pragma unroll
    for (int ks = 0; ks < 8; ++ks) {
        int aslot = ((mi * 8 + ks) * 64 + lane) * 8;
        bf16x8 a_h = *(const bf16x8*)&Ah[aslot];
        bf16x8 a_l = *(const bf16x8*)&Al[aslot];
#pragma unroll
        for (int nf = 0; nf < 2; ++nf) {
            int ntile = nh * 2 + nf;
            int slot = ((ntile * 8 + ks) * 64 + lane) * 8;
            bf16x8 b_h = *(const bf16x8*)&W2fh[slot];
            bf16x8 b_l = *(const bf16x8*)&W2fl[slot];
            acc2[nf] = __builtin_amdgcn_mfma_f32_16x16x32_bf16(a_h, b_h, acc2[nf], 0, 0, 0);
            acc2[nf] = __builtin_amdgcn_mfma_f32_16x16x32_bf16(a_h, b_l, acc2[nf], 0, 0, 0);
            acc2[nf] = __builtin_amdgcn_mfma_f32_16x16x32_bf16(a_l, b_h, acc2[nf], 0, 0, 0);
        }
    }

    int fq = lane >> 4, fr = lane & 15;
#pragma unroll
    for (int j = 0; j < 4; ++j) {
        int r = n0 + mi * 16 + fq * 4 + j;
        if (r >= N_NODES) continue;
#pragma unroll
        for (int nf = 0; nf < 2; ++nf) {
            int c = (nh * 2 + nf) * 16 + fr;
            feat2b[(size_t)r * OUT_DIM + c] = bfh(acc2[nf][j]);
        }
    }

    float al_v[2], ar_v[2];
#pragma unroll
    for (int nf = 0; nf < 2; ++nf) {
        al_v[nf] = al2[(nh * 2 + nf) * 16 + fr];
        ar_v[nf] = ar2[(nh * 2 + nf) * 16 + fr];
    }
#pragma unroll
    for (int j = 0; j < 4; ++j) {
        float l = acc2[0][j] * al_v[0] + acc2[1][j] * al_v[1];
        float r = acc2[0][j] * ar_v[0] + acc2[1][j] * ar_v[1];
#pragma unroll
        for (int off = 1; off < 16; off <<= 1) {
            l += __shfl_xor(l, off, 64);
            r += __shfl_xor(r, off, 64);
        }
        if (fr == 0) {
            pl[nh][mi][fq * 4 + j] = l;
            pr[nh][mi][fq * 4 + j] = r;
        }
    }
    __syncthreads();
    if (t < 32) {
        int n = n0 + t;
        if (n < N_NODES) {
            int mi2 = t >> 4, rr = t & 15;
            el2[n] = pl[0][mi2][rr] + pl[1][mi2][rr];
            er2[n] = pr[0][mi2][rr] + pr[1][mi2][rr];
        }
    }
}

// ---------------- gather2: register softmax + aggregate + bias, 4 dsts/block, no LDS ----------------
__global__ __launch_bounds__(256) void gather2_kernel(const int* __restrict__ row,
                                                      const int* __restrict__ perm_src,
                                                      const float* __restrict__ el2,
                                                      const float* __restrict__ er2,
                                                      const unsigned short* __restrict__ feat2b,
                                                      const float* __restrict__ b2,
                                                      float* __restrict__ out) {
    int tid = threadIdx.x;
    int w = tid >> 6, lane = tid & 63;
    int d = blockIdx.x * 4 + w;
    int base = row[d], deg = row[d + 1] - base;
    float bias = b2[lane];
    if (deg == 0) {
        out[(size_t)d * OUT_DIM + lane] = bias;
        return;
    }
    if (deg <= 64) {
        int s_reg = (lane < deg) ? perm_src[base + lane] : 0;
        float er_d = er2[d];
        float sc = (lane < deg) ? leaky(el2[s_reg] + er_d) : -1e30f;
        float m = sc;
#pragma unroll
        for (int off = 1; off < 64; off <<= 1) m = fmaxf(m, __shfl_xor(m, off, 64));
        float ex = (lane < deg) ? __expf(sc - m) : 0.f;
        float ss = ex;
#pragma unroll
        for (int off = 1; off < 64; off <<= 1) ss += __shfl_xor(ss, off, 64);
        float alpha = ex / ss;
        float a0 = 0.f, a1 = 0.f, a2 = 0.f, a3 = 0.f;
        int j = 0;
        for (; j + 3 < deg; j += 4) {
            int s0 = __shfl(s_reg, j), s1 = __shfl(s_reg, j + 1);
            int s2 = __shfl(s_reg, j + 2), s3 = __shfl(s_reg, j + 3);
            float w0 = __shfl(alpha, j), w1 = __shfl(alpha, j + 1);
            float w2 = __shfl(alpha, j + 2), w3 = __shfl(alpha, j + 3);
            a0 += w0 * fb(feat2b[(size_t)s0 * OUT_DIM + lane]);
            a1 += w1 * fb(feat2b[(size_t)s1 * OUT_DIM + lane]);
            a2 += w2 * fb(feat2b[(size_t)s2 * OUT_DIM + lane]);
            a3 += w3 * fb(feat2b[(size_t)s3 * OUT_DIM + lane]);
        }
        for (; j < deg; ++j) {
            int s0 = __shfl(s_reg, j);
            float w0 = __shfl(alpha, j);
            a0 += w0 * fb(feat2b[(size_t)s0 * OUT_DIM + lane]);
        }
        out[(size_t)d * OUT_DIM + lane] = a0 + a1 + a2 + a3 + bias;
    } else {
        // rare fallback deg > 64: recompute path
        float er_d = er2[d];
        float m = -1e30f;
        for (int j = lane; j < deg; j += 64)
            m = fmaxf(m, leaky(el2[perm_src[base + j]] + er_d));
#pragma unroll
        for (int off = 1; off < 64; off <<= 1) m = fmaxf(m, __shfl_xor(m, off, 64));
        float ss = 0.f;
        for (int j = lane; j < deg; j += 64)
            ss += __expf(leaky(el2[perm_src[base + j]] + er_d) - m);
#pragma unroll
        for (int off = 1; off < 64; off <<= 1) ss += __shfl_xor(ss, off, 64);
        float inv = 1.f / ss;
        float a0 = 0.f;
        for (int j = 0; j < deg; ++j) {
            int s = perm_src[base + j];
            float a = __expf(leaky(el2[s] + er_d) - m) * inv;
            a0 += a * fb(feat2b[(size_t)s * OUT_DIM + lane]);
        }
        out[(size_t)d * OUT_DIM + lane] = a0 + bias;
    }
}

extern "C" void kernel_launch(void* const* d_in, const int* in_sizes, int n_in,
                              void* d_out, int out_size, void* d_ws, size_t ws_size,
                              hipStream_t stream) {
    const float* features = (const float*)d_in[0];
    const int* src = (const int*)d_in[1];
    const int* dst = (const int*)d_in[2];
    const float* W1 = (const float*)d_in[3];
    const float* al1 = (const float*)d_in[4];
    const float* ar1 = (const float*)d_in[5];
    const float* b1 = (const float*)d_in[6];
    const float* W2 = (const float*)d_in[7];
    const float* al2 = (const float*)d_in[8];
    const float* ar2 = (const float*)d_in[9];
    const float* b2 = (const float*)d_in[10];
    float* out = (float*)d_out;

    // workspace layout
    float* ws = (float*)d_ws;
    float* el1 = ws;                                           // N*4
    float* er1 = el1 + N_NODES * HEADS;                        // N*4
    float* el2 = er1 + N_NODES * HEADS;                        // N
    float* er2 = el2 + N_NODES;                                // N
    unsigned short* feat1b = (unsigned short*)(er2 + N_NODES); // N*256 bf16
    unsigned short* feat2b = feat1b + (size_t)N_NODES * L1_OUT;// N*64 bf16
    unsigned short* W1fh = feat2b + (size_t)N_NODES * OUT_DIM; // 32768
    unsigned short* W1fl = W1fh + 32768;                       // 32768
    unsigned short* W2fh = W1fl + 32768;                       // 16384
    unsigned short* W2fl = W2fh + 16384;                       // 16384
    int* cnt = (int*)(W2fl + 16384);                           // N
    int* fc = cnt + N_NODES;                                   // N
    int* texcl = fc + N_NODES;                                 // N
    int* bsum = texcl + N_NODES;                               // 256
    int* bexcl = bsum + 256;                                   // 256
    int* row = bexcl + 256;                                    // N+1
    int* perm_src = row + N_NODES + 1;                         // E

    const int nscan = (N_NODES + SCAN_B - 1) / SCAN_B;   // 196

    hipMemsetAsync(cnt, 0, (size_t)2 * N_NODES * sizeof(int), stream);  // cnt + fc

    // CSR build + weight prep
    hist_wprep_kernel<<<HIST_B + 24, 256, 0, stream>>>(dst, cnt, W1, W2, W1fh, W1fl, W2fh, W2fl);
    scanA_kernel<<<nscan, SCAN_B, 0, stream>>>(cnt, texcl, bsum);
    scanB_kernel<<<1, SCAN_B, 0, stream>>>(bsum, bexcl, nscan);
    scanC_kernel<<<(N_NODES + 255) / 256, 256, 0, stream>>>(texcl, bexcl, row);
    fill_kernel<<<(N_EDGES + 255) / 256, 256, 0, stream>>>(src, dst, row, fc, perm_src);

    // layer 1 GEMM (+el1/er1)
    gemm1_kernel<<<(N_NODES + 63) / 64, 512, 0, stream>>>(features, W1fh, W1fl, al1, ar1,
                                                          feat1b, el1, er1);
    // layer 1 gather fused with layer 2 GEMM (+el2/er2)
    layer2_kernel<<<(N_NODES + 31) / 32, 256, 0, stream>>>(row, perm_src, el1, er1, feat1b,
                                                           b1, W2fh, W2fl, al2, ar2,
                                                           feat2b, el2, er2);
    // layer 2 gather (+bias)
    gather2_kernel<<<N_NODES / 4, 256, 0, stream>>>(row, perm_src, el2, er2, feat2b, b2, out);
}

// Round 7
// 163.171 us; speedup vs baseline: 2.2696x; 1.1135x over previous
//
#include <hip/hip_runtime.h>
#include <hip/hip_bf16.h>

#define N_NODES 50000
#define N_EDGES 400000
#define IN_DIM 128
#define HID 64
#define HEADS 4
#define L1_OUT (HEADS * HID)   // 256
#define OUT_DIM 64
#define NEG_SLOPE 0.2f
#define SCAN_B 256
#define HIST_B 1563            // ceil(400000/256)

typedef short bf16x8 __attribute__((ext_vector_type(8)));
typedef float f32x4 __attribute__((ext_vector_type(4)));

__device__ __forceinline__ float leaky(float x) { return x > 0.f ? x : NEG_SLOPE * x; }

// RNE float->bf16 bits, bf16 bits->float
__device__ __forceinline__ unsigned short bfh(float x) {
    unsigned u = __float_as_uint(x);
    return (unsigned short)((u + 0x7fffu + ((u >> 16) & 1u)) >> 16);
}
__device__ __forceinline__ float fb(unsigned short h) {
    return __uint_as_float(((unsigned)h) << 16);
}

// LDS A-frag slot swizzle (16B-slot index u): spreads kstep/g into the bank bits.
// Applied identically at write and read; permutes only bits [2:0].
__device__ __forceinline__ int swzA(int u) {
    return u ^ (((u >> 6) & 7) ^ (((u >> 4) & 3) << 1));
}

// ---------------- CSR hist + W fragment prep (merged) ----------------
__global__ void hist_wprep_kernel(const int* __restrict__ dst, int* __restrict__ cnt,
                                  const float* __restrict__ W1, const float* __restrict__ W2,
                                  unsigned short* __restrict__ W1fh, unsigned short* __restrict__ W1fl,
                                  unsigned short* __restrict__ W2fh, unsigned short* __restrict__ W2fl) {
    int bid = blockIdx.x;
    if (bid < HIST_B) {
        int e = bid * 256 + threadIdx.x;
        if (e < N_EDGES) atomicAdd(&cnt[dst[e]], 1);
        return;
    }
    int s = (bid - HIST_B) * 256 + threadIdx.x;
    if (s < 4096) {
        int lane = s & 63, ks = (s >> 6) & 3, ntile = s >> 8;
        int n = ntile * 16 + (lane & 15);
        int kb = ks * 32 + (lane >> 4) * 8;
#pragma unroll
        for (int j = 0; j < 8; ++j) {
            float w = W1[(kb + j) * L1_OUT + n];
            unsigned short h = bfh(w);
            W1fh[s * 8 + j] = h;
            W1fl[s * 8 + j] = bfh(w - fb(h));
        }
    } else if (s < 6144) {
        int s2 = s - 4096;
        int lane = s2 & 63, ks = (s2 >> 6) & 7, ntile = s2 >> 9;
        int n = ntile * 16 + (lane & 15);
        int kb = ks * 32 + (lane >> 4) * 8;
#pragma unroll
        for (int j = 0; j < 8; ++j) {
            float w = W2[(kb + j) * OUT_DIM + n];
            unsigned short h = bfh(w);
            W2fh[s2 * 8 + j] = h;
            W2fl[s2 * 8 + j] = bfh(w - fb(h));
        }
    }
}

__global__ void scanA_kernel(const int* __restrict__ cnt, int* __restrict__ texcl,
                             int* __restrict__ bsum) {
    __shared__ int sh[SCAN_B];
    int tid = threadIdx.x;
    int i = blockIdx.x * SCAN_B + tid;
    int v = (i < N_NODES) ? cnt[i] : 0;
    sh[tid] = v;
    __syncthreads();
    for (int off = 1; off < SCAN_B; off <<= 1) {
        int t = (tid >= off) ? sh[tid - off] : 0;
        __syncthreads();
        sh[tid] += t;
        __syncthreads();
    }
    if (i < N_NODES) texcl[i] = sh[tid] - v;
    if (tid == SCAN_B - 1) bsum[blockIdx.x] = sh[tid];
}

__global__ void scanB_kernel(const int* __restrict__ bsum, int* __restrict__ bexcl, int nb) {
    __shared__ int sh[SCAN_B];
    int tid = threadIdx.x;
    int v = (tid < nb) ? bsum[tid] : 0;
    sh[tid] = v;
    __syncthreads();
    for (int off = 1; off < SCAN_B; off <<= 1) {
        int t = (tid >= off) ? sh[tid - off] : 0;
        __syncthreads();
        sh[tid] += t;
        __syncthreads();
    }
    if (tid < nb) bexcl[tid] = sh[tid] - v;
}

__global__ void scanC_kernel(const int* __restrict__ texcl, const int* __restrict__ bexcl,
                             int* __restrict__ row) {
    int i = blockIdx.x * blockDim.x + threadIdx.x;
    if (i < N_NODES) row[i] = texcl[i] + bexcl[i >> 8];
    if (blockIdx.x == 0 && threadIdx.x == 0) row[N_NODES] = N_EDGES;
}

__global__ void fill_kernel(const int* __restrict__ src, const int* __restrict__ dst,
                            const int* __restrict__ row, int* __restrict__ fc,
                            int* __restrict__ perm_src) {
    int e = blockIdx.x * blockDim.x + threadIdx.x;
    if (e >= N_EDGES) return;
    int d = dst[e];
    int p = row[d] + atomicAdd(&fc[d], 1);
    perm_src[p] = src[e];
}

// ---------------- gemm1 (MFMA): feat1b = bf16(X @ W1) + fused el1/er1 ----------------
__global__ __launch_bounds__(512) void gemm1_kernel(const float* __restrict__ X,
                                                    const unsigned short* __restrict__ W1fh,
                                                    const unsigned short* __restrict__ W1fl,
                                                    const float* __restrict__ al1,
                                                    const float* __restrict__ ar1,
                                                    unsigned short* __restrict__ feat1b,
                                                    float* __restrict__ el1,
                                                    float* __restrict__ er1) {
    __shared__ unsigned short Ah[4 * 4 * 64 * 8];   // [mfrag][kstep][lane][j]
    __shared__ unsigned short Al[4 * 4 * 64 * 8];
    int t = threadIdx.x;
    int m0 = blockIdx.x * 64;

    {
        int m = t >> 3;
        int k0 = (t & 7) * 16;
        int mfrag = m >> 4, mrow = m & 15;
        bool valid = (m0 + m) < N_NODES;
        const float4* xr = (const float4*)&X[(size_t)(m0 + m) * IN_DIM];
#pragma unroll
        for (int g = 0; g < 4; ++g) {
            int k = k0 + g * 4;
            float4 v = valid ? xr[k >> 2] : float4{0.f, 0.f, 0.f, 0.f};
            int kstep = k >> 5, kk = k & 31;
            int lane = mrow + 16 * (kk >> 3);
            int j0 = kk & 7;
            int base = ((mfrag * 4 + kstep) * 64 + lane) * 8 + j0;
            unsigned short h0 = bfh(v.x), h1 = bfh(v.y), h2 = bfh(v.z), h3 = bfh(v.w);
            *(ushort4*)&Ah[base] = make_ushort4(h0, h1, h2, h3);
            *(ushort4*)&Al[base] = make_ushort4(bfh(v.x - fb(h0)), bfh(v.y - fb(h1)),
                                                bfh(v.z - fb(h2)), bfh(v.w - fb(h3)));
        }
    }
    __syncthreads();

    int w = t >> 6, lane = t & 63;
    int wr = w >> 2, wc = w & 3;   // wave tile: rows wr*32..+31, cols wc*64..+63 (head wc)
    f32x4 acc[2][4];
#pragma unroll
    for (int mi = 0; mi < 2; ++mi)
#pragma unroll
        for (int nf = 0; nf < 4; ++nf) acc[mi][nf] = f32x4{0.f, 0.f, 0.f, 0.f};

#pragma unroll
    for (int kstep = 0; kstep < 4; ++kstep) {
        bf16x8 a_h[2], a_l[2];
#pragma unroll
        for (int mi = 0; mi < 2; ++mi) {
            int slot = (((wr * 2 + mi) * 4 + kstep) * 64 + lane) * 8;
            a_h[mi] = *(const bf16x8*)&Ah[slot];
            a_l[mi] = *(const bf16x8*)&Al[slot];
        }
#pragma unroll
        for (int nf = 0; nf < 4; ++nf) {
            int slot = (((wc * 4 + nf) * 4 + kstep) * 64 + lane) * 8;
            bf16x8 b_h = *(const bf16x8*)&W1fh[slot];
            bf16x8 b_l = *(const bf16x8*)&W1fl[slot];
#pragma unroll
            for (int mi = 0; mi < 2; ++mi) {
                acc[mi][nf] = __builtin_amdgcn_mfma_f32_16x16x32_bf16(a_h[mi], b_h, acc[mi][nf], 0, 0, 0);
                acc[mi][nf] = __builtin_amdgcn_mfma_f32_16x16x32_bf16(a_h[mi], b_l, acc[mi][nf], 0, 0, 0);
                acc[mi][nf] = __builtin_amdgcn_mfma_f32_16x16x32_bf16(a_l[mi], b_h, acc[mi][nf], 0, 0, 0);
            }
        }
    }

    int fq = lane >> 4, fr = lane & 15;
#pragma unroll
    for (int mi = 0; mi < 2; ++mi) {
#pragma unroll
        for (int j = 0; j < 4; ++j) {
            int r = m0 + wr * 32 + mi * 16 + fq * 4 + j;
            if (r >= N_NODES) continue;
#pragma unroll
            for (int nf = 0; nf < 4; ++nf) {
                int c = wc * 64 + nf * 16 + fr;
                feat1b[(size_t)r * L1_OUT + c] = bfh(acc[mi][nf][j]);
            }
        }
    }

    float al_v[4], ar_v[4];
#pragma unroll
    for (int nf = 0; nf < 4; ++nf) {
        al_v[nf] = al1[wc * 64 + nf * 16 + fr];
        ar_v[nf] = ar1[wc * 64 + nf * 16 + fr];
    }
#pragma unroll
    for (int mi = 0; mi < 2; ++mi) {
#pragma unroll
        for (int j = 0; j < 4; ++j) {
            float l = 0.f, r = 0.f;
#pragma unroll
            for (int nf = 0; nf < 4; ++nf) {
                l += acc[mi][nf][j] * al_v[nf];
                r += acc[mi][nf][j] * ar_v[nf];
            }
#pragma unroll
            for (int off = 1; off < 16; off <<= 1) {
                l += __shfl_xor(l, off, 64);
                r += __shfl_xor(r, off, 64);
            }
            int rr = m0 + wr * 32 + mi * 16 + fq * 4 + j;
            if (fr == 0 && rr < N_NODES) {
                el1[rr * HEADS + wc] = l;
                er1[rr * HEADS + wc] = r;
            }
        }
    }
}

// ---------------- layer2 fused: gather1 (into LDS A-frags) + gemm2 MFMA + el2/er2 ----------------
// Block = 512 threads = 8 waves, owns 32 consecutive dsts (4 iterations x 8 waves).
__global__ __launch_bounds__(512, 8) void layer2_kernel(const int* __restrict__ row,
                                                        const int* __restrict__ perm_src,
                                                        const float* __restrict__ el1,
                                                        const float* __restrict__ er1,
                                                        const unsigned short* __restrict__ feat1b,
                                                        const float* __restrict__ b1,
                                                        const unsigned short* __restrict__ W2fh,
                                                        const unsigned short* __restrict__ W2fl,
                                                        const float* __restrict__ al2,
                                                        const float* __restrict__ ar2,
                                                        unsigned short* __restrict__ feat2b,
                                                        float* __restrict__ el2,
                                                        float* __restrict__ er2) {
    __shared__ unsigned short Ah[2 * 8 * 64 * 8];   // [mfrag][kstep][lane][j] 16 KB (swizzled slots)
    __shared__ unsigned short Al[2 * 8 * 64 * 8];   // 16 KB
    __shared__ float pl[2][4][16], pr[2][4][16];    // [mi][ntile][row]
    int t = threadIdx.x;
    int w = t >> 6, lane = t & 63;
    int n0 = blockIdx.x * 32;

    float4 b1v = *(const float4*)&b1[lane * 4];   // channels lane*4..+3
    const ushort4* f4 = (const ushort4*)feat1b;

    // ---- phase 1: aggregate 32 dst rows into LDS A-fragments (hi/lo bf16) ----
#pragma unroll 1
    for (int it = 0; it < 4; ++it) {
        int d = n0 + it * 8 + w;
        float4 acc = {0.f, 0.f, 0.f, 0.f};
        bool valid = d < N_NODES;
        if (valid) {
            int base = row[d], deg = row[d + 1] - base;
            if (deg > 0 && deg <= 16) {
                // register softmax: 16-lane group per head, lane jj = edge jj
                int h = lane >> 4, jj = lane & 15;
                int s_reg = (jj < deg) ? perm_src[base + jj] : 0;
                float er_d = er1[d * HEADS + h];
                float sc = (jj < deg) ? leaky(el1[s_reg * HEADS + h] + er_d) : -1e30f;
                float m = sc;
                m = fmaxf(m, __shfl_xor(m, 1, 64));
                m = fmaxf(m, __shfl_xor(m, 2, 64));
                m = fmaxf(m, __shfl_xor(m, 4, 64));
                m = fmaxf(m, __shfl_xor(m, 8, 64));
                float ex = (jj < deg) ? __expf(sc - m) : 0.f;
                float ss = ex;
                ss += __shfl_xor(ss, 1, 64);
                ss += __shfl_xor(ss, 2, 64);
                ss += __shfl_xor(ss, 4, 64);
                ss += __shfl_xor(ss, 8, 64);
                float alpha = ex / ss;
                int hb = lane & 48;
                float4 A0 = {0.f,0.f,0.f,0.f}, A1 = {0.f,0.f,0.f,0.f};
                float4 A2 = {0.f,0.f,0.f,0.f}, A3 = {0.f,0.f,0.f,0.f};
                int j = 0;
                for (; j + 3 < deg; j += 4) {
                    int s0 = __shfl(s_reg, j), s1 = __shfl(s_reg, j + 1);
                    int s2 = __shfl(s_reg, j + 2), s3 = __shfl(s_reg, j + 3);
                    float a0 = __shfl(alpha, hb + j), a1 = __shfl(alpha, hb + j + 1);
                    float a2 = __shfl(alpha, hb + j + 2), a3 = __shfl(alpha, hb + j + 3);
                    ushort4 f0 = f4[(size_t)s0 * 64 + lane];
                    ushort4 f1 = f4[(size_t)s1 * 64 + lane];
                    ushort4 f2 = f4[(size_t)s2 * 64 + lane];
                    ushort4 f3 = f4[(size_t)s3 * 64 + lane];
                    A0.x += a0 * fb(f0.x); A0.y += a0 * fb(f0.y); A0.z += a0 * fb(f0.z); A0.w += a0 * fb(f0.w);
                    A1.x += a1 * fb(f1.x); A1.y += a1 * fb(f1.y); A1.z += a1 * fb(f1.z); A1.w += a1 * fb(f1.w);
                    A2.x += a2 * fb(f2.x); A2.y += a2 * fb(f2.y); A2.z += a2 * fb(f2.z); A2.w += a2 * fb(f2.w);
                    A3.x += a3 * fb(f3.x); A3.y += a3 * fb(f3.y); A3.z += a3 * fb(f3.z); A3.w += a3 * fb(f3.w);
                }
                for (; j < deg; ++j) {
                    int s0 = __shfl(s_reg, j);
                    float a0 = __shfl(alpha, hb + j);
                    ushort4 f0 = f4[(size_t)s0 * 64 + lane];
                    A0.x += a0 * fb(f0.x); A0.y += a0 * fb(f0.y); A0.z += a0 * fb(f0.z); A0.w += a0 * fb(f0.w);
                }
                acc.x = A0.x + A1.x + A2.x + A3.x;
                acc.y = A0.y + A1.y + A2.y + A3.y;
                acc.z = A0.z + A1.z + A2.z + A3.z;
                acc.w = A0.w + A1.w + A2.w + A3.w;
            } else if (deg > 16) {
                // rare fallback: strided per-head stats, serial recompute aggregation
                float mh0, mh1, mh2, mh3, iv0, iv1, iv2, iv3;
#pragma unroll
                for (int h = 0; h < 4; ++h) {
                    float er_dh = er1[d * HEADS + h];
                    float m = -1e30f;
                    for (int j = lane; j < deg; j += 64)
                        m = fmaxf(m, leaky(el1[perm_src[base + j] * HEADS + h] + er_dh));
#pragma unroll
                    for (int off = 1; off < 64; off <<= 1) m = fmaxf(m, __shfl_xor(m, off, 64));
                    float ss = 0.f;
                    for (int j = lane; j < deg; j += 64)
                        ss += __expf(leaky(el1[perm_src[base + j] * HEADS + h] + er_dh) - m);
#pragma unroll
                    for (int off = 1; off < 64; off <<= 1) ss += __shfl_xor(ss, off, 64);
                    float iv = 1.f / ss;
                    if (h == 0) { mh0 = m; iv0 = iv; }
                    else if (h == 1) { mh1 = m; iv1 = iv; }
                    else if (h == 2) { mh2 = m; iv2 = iv; }
                    else { mh3 = m; iv3 = iv; }
                }
                int hh = lane >> 4;
                float m_s = hh == 0 ? mh0 : hh == 1 ? mh1 : hh == 2 ? mh2 : mh3;
                float iv_s = hh == 0 ? iv0 : hh == 1 ? iv1 : hh == 2 ? iv2 : iv3;
                float er_s = er1[d * HEADS + hh];
                for (int j = 0; j < deg; ++j) {
                    int s = perm_src[base + j];
                    float a = __expf(leaky(el1[s * HEADS + hh] + er_s) - m_s) * iv_s;
                    ushort4 f0 = f4[(size_t)s * 64 + lane];
                    acc.x += a * fb(f0.x); acc.y += a * fb(f0.y);
                    acc.z += a * fb(f0.z); acc.w += a * fb(f0.w);
                }
            }
            // deg==0: acc stays 0
            acc.x += b1v.x; acc.y += b1v.y; acc.z += b1v.z; acc.w += b1v.w;
        }
        // write row m = it*8+w, channels lane*4..+3 into swizzled A-frag layout (hi/lo)
        int m = it * 8 + w;
        int mfrag = m >> 4, mrow = m & 15;
        int c = lane * 4;
        int kstep = c >> 5;
        int g = (c & 31) >> 3;
        int u = (mfrag * 8 + kstep) * 64 + mrow + 16 * g;
        int basei = swzA(u) * 8 + (c & 7);
        unsigned short h0 = bfh(acc.x), h1 = bfh(acc.y), h2 = bfh(acc.z), h3 = bfh(acc.w);
        *(ushort4*)&Ah[basei] = make_ushort4(h0, h1, h2, h3);
        *(ushort4*)&Al[basei] = make_ushort4(bfh(acc.x - fb(h0)), bfh(acc.y - fb(h1)),
                                             bfh(acc.z - fb(h2)), bfh(acc.w - fb(h3)));
    }
    __syncthreads();

    // ---- phase 2: gemm2 MFMA; wave = (mi, ntile), 16x16 output each ----
    int mi = w & 1, ntile = w >> 1;
    f32x4 acc2 = f32x4{0.f, 0.f, 0.f, 0.f};

#pragma unroll
    for (int ks = 0; ks < 8; ++ks) {
        int aslot = swzA((mi * 8 + ks) * 64 + lane) * 8;
        bf16x8 a_h = *(const bf16x8*)&Ah[aslot];
        bf16x8 a_l = *(const bf16x8*)&Al[aslot];
        int slot = ((ntile * 8 + ks) * 64 + lane) * 8;
        bf16x8 b_h = *(const bf16x8*)&W2fh[slot];
        bf16x8 b_l = *(const bf16x8*)&W2fl[slot];
        acc2 = __builtin_amdgcn_mfma_f32_16x16x32_bf16(a_h, b_h, acc2, 0, 0, 0);
        acc2 = __builtin_amdgcn_mfma_f32_16x16x32_bf16(a_h, b_l, acc2, 0, 0, 0);
        acc2 = __builtin_amdgcn_mfma_f32_16x16x32_bf16(a_l, b_h, acc2, 0, 0, 0);
    }

    int fq = lane >> 4, fr = lane & 15;
#pragma unroll
    for (int j = 0; j < 4; ++j) {
        int r = n0 + mi * 16 + fq * 4 + j;
        if (r < N_NODES) {
            int c = ntile * 16 + fr;
            feat2b[(size_t)r * OUT_DIM + c] = bfh(acc2[j]);
        }
    }

    // fused el2/er2: per-wave partial over 16 cols, combine 4 ntiles in LDS
    float al_v = al2[ntile * 16 + fr];
    float ar_v = ar2[ntile * 16 + fr];
#pragma unroll
    for (int j = 0; j < 4; ++j) {
        float l = acc2[j] * al_v;
        float r = acc2[j] * ar_v;
#pragma unroll
        for (int off = 1; off < 16; off <<= 1) {
            l += __shfl_xor(l, off, 64);
            r += __shfl_xor(r, off, 64);
        }
        if (fr == 0) {
            pl[mi][ntile][fq * 4 + j] = l;
            pr[mi][ntile][fq * 4 + j] = r;
        }
    }
    __syncthreads();
    if (t < 32) {
        int n = n0 + t;
        if (n < N_NODES) {
            int mi2 = t >> 4, rr = t & 15;
            el2[n] = pl[mi2][0][rr] + pl[mi2][1][rr] + pl[mi2][2][rr] + pl[mi2][3][rr];
            er2[n] = pr[mi2][0][rr] + pr[mi2][1][rr] + pr[mi2][2][rr] + pr[mi2][3][rr];
        }
    }
}

// ---------------- gather2: register softmax + aggregate + bias, 4 dsts/block, no LDS ----------------
__global__ __launch_bounds__(256) void gather2_kernel(const int* __restrict__ row,
                                                      const int* __restrict__ perm_src,
                                                      const float* __restrict__ el2,
                                                      const float* __restrict__ er2,
                                                      const unsigned short* __restrict__ feat2b,
                                                      const float* __restrict__ b2,
                                                      float* __restrict__ out) {
    int tid = threadIdx.x;
    int w = tid >> 6, lane = tid & 63;
    int d = blockIdx.x * 4 + w;
    int base = row[d], deg = row[d + 1] - base;
    float bias = b2[lane];
    if (deg == 0) {
        out[(size_t)d * OUT_DIM + lane] = bias;
        return;
    }
    if (deg <= 64) {
        int s_reg = (lane < deg) ? perm_src[base + lane] : 0;
        float er_d = er2[d];
        float sc = (lane < deg) ? leaky(el2[s_reg] + er_d) : -1e30f;
        float m = sc;
#pragma unroll
        for (int off = 1; off < 64; off <<= 1) m = fmaxf(m, __shfl_xor(m, off, 64));
        float ex = (lane < deg) ? __expf(sc - m) : 0.f;
        float ss = ex;
#pragma unroll
        for (int off = 1; off < 64; off <<= 1) ss += __shfl_xor(ss, off, 64);
        float alpha = ex / ss;
        float a0 = 0.f, a1 = 0.f, a2 = 0.f, a3 = 0.f;
        int j = 0;
        for (; j + 3 < deg; j += 4) {
            int s0 = __shfl(s_reg, j), s1 = __shfl(s_reg, j + 1);
            int s2 = __shfl(s_reg, j + 2), s3 = __shfl(s_reg, j + 3);
            float w0 = __shfl(alpha, j), w1 = __shfl(alpha, j + 1);
            float w2 = __shfl(alpha, j + 2), w3 = __shfl(alpha, j + 3);
            a0 += w0 * fb(feat2b[(size_t)s0 * OUT_DIM + lane]);
            a1 += w1 * fb(feat2b[(size_t)s1 * OUT_DIM + lane]);
            a2 += w2 * fb(feat2b[(size_t)s2 * OUT_DIM + lane]);
            a3 += w3 * fb(feat2b[(size_t)s3 * OUT_DIM + lane]);
        }
        for (; j < deg; ++j) {
            int s0 = __shfl(s_reg, j);
            float w0 = __shfl(alpha, j);
            a0 += w0 * fb(feat2b[(size_t)s0 * OUT_DIM + lane]);
        }
        out[(size_t)d * OUT_DIM + lane] = a0 + a1 + a2 + a3 + bias;
    } else {
        // rare fallback deg > 64: recompute path
        float er_d = er2[d];
        float m = -1e30f;
        for (int j = lane; j < deg; j += 64)
            m = fmaxf(m, leaky(el2[perm_src[base + j]] + er_d));
#pragma unroll
        for (int off = 1; off < 64; off <<= 1) m = fmaxf(m, __shfl_xor(m, off, 64));
        float ss = 0.f;
        for (int j = lane; j < deg; j += 64)
            ss += __expf(leaky(el2[perm_src[base + j]] + er_d) - m);
#pragma unroll
        for (int off = 1; off < 64; off <<= 1) ss += __shfl_xor(ss, off, 64);
        float inv = 1.f / ss;
        float a0 = 0.f;
        for (int j = 0; j < deg; ++j) {
            int s = perm_src[base + j];
            float a = __expf(leaky(el2[s] + er_d) - m) * inv;
            a0 += a * fb(feat2b[(size_t)s * OUT_DIM + lane]);
        }
        out[(size_t)d * OUT_DIM + lane] = a0 + bias;
    }
}

extern "C" void kernel_launch(void* const* d_in, const int* in_sizes, int n_in,
                              void* d_out, int out_size, void* d_ws, size_t ws_size,
                              hipStream_t stream) {
    const float* features = (const float*)d_in[0];
    const int* src = (const int*)d_in[1];
    const int* dst = (const int*)d_in[2];
    const float* W1 = (const float*)d_in[3];
    const float* al1 = (const float*)d_in[4];
    const float* ar1 = (const float*)d_in[5];
    const float* b1 = (const float*)d_in[6];
    const float* W2 = (const float*)d_in[7];
    const float* al2 = (const float*)d_in[8];
    const float* ar2 = (const float*)d_in[9];
    const float* b2 = (const float*)d_in[10];
    float* out = (float*)d_out;

    // workspace layout
    float* ws = (float*)d_ws;
    float* el1 = ws;                                           // N*4
    float* er1 = el1 + N_NODES * HEADS;                        // N*4
    float* el2 = er1 + N_NODES * HEADS;                        // N
    float* er2 = el2 + N_NODES;                                // N
    unsigned short* feat1b = (unsigned short*)(er2 + N_NODES); // N*256 bf16
    unsigned short* feat2b = feat1b + (size_t)N_NODES * L1_OUT;// N*64 bf16
    unsigned short* W1fh = feat2b + (size_t)N_NODES * OUT_DIM; // 32768
    unsigned short* W1fl = W1fh + 32768;                       // 32768
    unsigned short* W2fh = W1fl + 32768;                       // 16384
    unsigned short* W2fl = W2fh + 16384;                       // 16384
    int* cnt = (int*)(W2fl + 16384);                           // N
    int* fc = cnt + N_NODES;                                   // N
    int* texcl = fc + N_NODES;                                 // N
    int* bsum = texcl + N_NODES;                               // 256
    int* bexcl = bsum + 256;                                   // 256
    int* row = bexcl + 256;                                    // N+1
    int* perm_src = row + N_NODES + 1;                         // E

    const int nscan = (N_NODES + SCAN_B - 1) / SCAN_B;   // 196

    hipMemsetAsync(cnt, 0, (size_t)2 * N_NODES * sizeof(int), stream);  // cnt + fc

    // CSR build + weight prep
    hist_wprep_kernel<<<HIST_B + 24, 256, 0, stream>>>(dst, cnt, W1, W2, W1fh, W1fl, W2fh, W2fl);
    scanA_kernel<<<nscan, SCAN_B, 0, stream>>>(cnt, texcl, bsum);
    scanB_kernel<<<1, SCAN_B, 0, stream>>>(bsum, bexcl, nscan);
    scanC_kernel<<<(N_NODES + 255) / 256, 256, 0, stream>>>(texcl, bexcl, row);
    fill_kernel<<<(N_EDGES + 255) / 256, 256, 0, stream>>>(src, dst, row, fc, perm_src);

    // layer 1 GEMM (+el1/er1)
    gemm1_kernel<<<(N_NODES + 63) / 64, 512, 0, stream>>>(features, W1fh, W1fl, al1, ar1,
                                                          feat1b, el1, er1);
    // layer 1 gather fused with layer 2 GEMM (+el2/er2)
    layer2_kernel<<<(N_NODES + 31) / 32, 512, 0, stream>>>(row, perm_src, el1, er1, feat1b,
                                                           b1, W2fh, W2fl, al2, ar2,
                                                           feat2b, el2, er2);
    // layer 2 gather (+bias)
    gather2_kernel<<<N_NODES / 4, 256, 0, stream>>>(row, perm_src, el2, er2, feat2b, b2, out);
}